// Round 5
// baseline (1520.096 us; speedup 1.0000x reference)
//
#include <hip/hip_runtime.h>
#include <hip/hip_bf16.h>

#define D_MODEL 2048
#define NUM_HEADS 16
#define D_FF 8192
#define BATCH 4
#define SEQ 2048
#define DK 128
#define MTOT (BATCH * SEQ)  // 8192

typedef __attribute__((ext_vector_type(8))) short short8;
typedef __attribute__((ext_vector_type(4))) short short4v;
typedef __attribute__((ext_vector_type(4))) float f32x4;

#define MFMA16(a, b, c) __builtin_amdgcn_mfma_f32_16x16x32_bf16(a, b, c, 0, 0, 0)

#define GLOAD16(gp, lp)                                                        \
  __builtin_amdgcn_global_load_lds(                                            \
      (const __attribute__((address_space(1))) void*)(gp),                     \
      (__attribute__((address_space(3))) void*)(lp), 16, 0, 0)

static __device__ __forceinline__ unsigned short f2bf(float f) {
  return __builtin_bit_cast(unsigned short, __float2bfloat16(f));
}

// ---------------------------------------------------------------------------
// Weight convert + transpose: in f32 [K][N] -> out bf16 [N][K]
// ---------------------------------------------------------------------------
__global__ __launch_bounds__(256) void transpose_cvt_kernel(
    const float* __restrict__ in, __hip_bfloat16* __restrict__ out, int K, int N) {
  __shared__ float tile[32][33];
  const int n0 = blockIdx.x * 32, k0 = blockIdx.y * 32;
  const int tx = threadIdx.x & 31, ty = threadIdx.x >> 5;  // 32 x 8
#pragma unroll
  for (int i = 0; i < 4; ++i)
    tile[ty + i * 8][tx] = in[(size_t)(k0 + ty + i * 8) * N + n0 + tx];
  __syncthreads();
#pragma unroll
  for (int i = 0; i < 4; ++i)
    out[(size_t)(n0 + ty + i * 8) * K + k0 + tx] = __float2bfloat16(tile[tx][ty + i * 8]);
}

// ---------------------------------------------------------------------------
// LayerNorm: f32 [M][D_MODEL] -> bf16 [M][D_MODEL]
// ---------------------------------------------------------------------------
__global__ __launch_bounds__(256) void layernorm_kernel(
    const float* __restrict__ x, const float* __restrict__ g,
    const float* __restrict__ bta, __hip_bfloat16* __restrict__ out) {
  const int row = blockIdx.x;
  const int tid = threadIdx.x;
  const float* xr = x + (size_t)row * D_MODEL;
  float4 v0 = *(const float4*)(xr + tid * 8);
  float4 v1 = *(const float4*)(xr + tid * 8 + 4);
  float s = v0.x + v0.y + v0.z + v0.w + v1.x + v1.y + v1.z + v1.w;
  float q = v0.x * v0.x + v0.y * v0.y + v0.z * v0.z + v0.w * v0.w +
            v1.x * v1.x + v1.y * v1.y + v1.z * v1.z + v1.w * v1.w;
#pragma unroll
  for (int off = 1; off < 64; off <<= 1) {
    s += __shfl_xor(s, off);
    q += __shfl_xor(q, off);
  }
  __shared__ float rs[4], rq[4];
  if ((tid & 63) == 0) {
    rs[tid >> 6] = s;
    rq[tid >> 6] = q;
  }
  __syncthreads();
  s = rs[0] + rs[1] + rs[2] + rs[3];
  q = rq[0] + rq[1] + rq[2] + rq[3];
  const float mu = s * (1.0f / D_MODEL);
  const float var = q * (1.0f / D_MODEL) - mu * mu;
  const float rstd = rsqrtf(var + 1e-5f);
  float4 g0 = *(const float4*)(g + tid * 8);
  float4 g1 = *(const float4*)(g + tid * 8 + 4);
  float4 b0 = *(const float4*)(bta + tid * 8);
  float4 b1 = *(const float4*)(bta + tid * 8 + 4);
  short8 o;
  o[0] = (short)f2bf((v0.x - mu) * rstd * g0.x + b0.x);
  o[1] = (short)f2bf((v0.y - mu) * rstd * g0.y + b0.y);
  o[2] = (short)f2bf((v0.z - mu) * rstd * g0.z + b0.z);
  o[3] = (short)f2bf((v0.w - mu) * rstd * g0.w + b0.w);
  o[4] = (short)f2bf((v1.x - mu) * rstd * g1.x + b1.x);
  o[5] = (short)f2bf((v1.y - mu) * rstd * g1.y + b1.y);
  o[6] = (short)f2bf((v1.z - mu) * rstd * g1.z + b1.z);
  o[7] = (short)f2bf((v1.w - mu) * rstd * g1.w + b1.w);
  *(short8*)(out + (size_t)row * D_MODEL + tid * 8) = o;
}

// ---------------------------------------------------------------------------
// GEMM: C[M][N] = A[M][K] @ Bt[N][K]^T (+bias, epilogue variants)
// 256x256 tile, BK=32, 8 waves (2Mx4N), 4-deep LDS ring (128 KiB),
// counted vmcnt(8) pipeline: 2 K-tiles always in flight, one barrier/step.
// LDS rows 64B, read-swizzle blk ^= (row&3)^((row>>2)&3) (2-way = free);
// global source pre-swizzled with same involution (rule #21).
// ---------------------------------------------------------------------------
enum { EPI_BF16 = 0, EPI_VT = 1, EPI_RESID = 2, EPI_GELU = 3 };

template <int EPI>
__global__ __launch_bounds__(512, 2) void gemm_kernel(
    const __hip_bfloat16* __restrict__ A, const __hip_bfloat16* __restrict__ Bt,
    const float* __restrict__ bias, const float* __restrict__ resid,
    void* __restrict__ outv, int M, int N, int K, int nby) {
  __shared__ __align__(16) unsigned char lds[4][32768];  // [buf][A 16K | B 16K]
  const int tid = threadIdx.x;
  const int lane = tid & 63, w = tid >> 6;  // 8 waves
  const int l15 = lane & 15, lg = lane >> 4;
  // XCD-aware bijective swizzle (gridDim.x % 8 == 0); consecutive swz share bx
  const int bid = blockIdx.x;
  const int cpx = gridDim.x >> 3;
  const int swz = (bid & 7) * cpx + (bid >> 3);
  const int m0 = (swz % nby) * 256, n0 = (swz / nby) * 256;
  const int wm = (w >> 2) * 128, wn = (w & 3) * 64;

  // staging lane map: chunk = 16 rows x 64B; lane i -> row i>>2, 16B-block i&3
  const int rsub = lane >> 2;
  const int gblk = (lane & 3) ^ ((lane >> 2) & 3) ^ ((lane >> 4) & 3);
  // read swizzle: byte-offset of this lane's 16B block within its 64B row
  const int off16 = (lg ^ ((l15 & 3) ^ ((l15 >> 2) & 3))) << 4;

  const int cA = w * 2;  // this wave's chunk pair (covers chunks 0..15)
  const __hip_bfloat16* Asrc = A + (size_t)(m0 + cA * 16 + rsub) * K + gblk * 8;
  const __hip_bfloat16* Bsrc = Bt + (size_t)(n0 + cA * 16 + rsub) * K + gblk * 8;
  const size_t rstep = (size_t)16 * K;  // 16 rows = next chunk

  f32x4 acc[8][4] = {};
  const int nt = K >> 5;  // K-steps of 32

  auto STAGE = [&](int tt) {
    unsigned char* db = lds[tt & 3];
    const size_t ko = (size_t)tt * 32;
    GLOAD16(Asrc + ko, db + cA * 1024);
    GLOAD16(Asrc + rstep + ko, db + cA * 1024 + 1024);
    GLOAD16(Bsrc + ko, db + 16384 + cA * 1024);
    GLOAD16(Bsrc + rstep + ko, db + 16384 + cA * 1024 + 1024);
  };
  auto COMPUTE = [&](int tt) {
    const unsigned char* db = lds[tt & 3];
    short8 af[8], bfr[4];
#pragma unroll
    for (int fj = 0; fj < 4; ++fj)
      bfr[fj] = *(const short8*)(db + 16384 + (wn + fj * 16 + l15) * 64 + off16);
#pragma unroll
    for (int fi = 0; fi < 8; ++fi)
      af[fi] = *(const short8*)(db + (wm + fi * 16 + l15) * 64 + off16);
#pragma unroll
    for (int fi = 0; fi < 8; ++fi)
#pragma unroll
      for (int fj = 0; fj < 4; ++fj)
        acc[fi][fj] = MFMA16(af[fi], bfr[fj], acc[fi][fj]);
  };

  STAGE(0);
  STAGE(1);
  STAGE(2);
  for (int t = 0; t < nt - 2; ++t) {
    asm volatile("s_waitcnt vmcnt(8)" ::: "memory");  // my tile-t loads done
    __builtin_amdgcn_s_barrier();                     // all waves: t in LDS, t-1 reads done
    if (t + 3 < nt) STAGE(t + 3);                     // overwrites buf of tile t-1
    COMPUTE(t);
  }
  asm volatile("s_waitcnt vmcnt(4)" ::: "memory");
  __builtin_amdgcn_s_barrier();
  COMPUTE(nt - 2);
  asm volatile("s_waitcnt vmcnt(0)" ::: "memory");
  __builtin_amdgcn_s_barrier();
  COMPUTE(nt - 1);

#pragma unroll
  for (int fi = 0; fi < 8; ++fi) {
#pragma unroll
    for (int fj = 0; fj < 4; ++fj) {
      const int mb = m0 + wm + fi * 16 + lg * 4;
      const int n = n0 + wn + fj * 16 + l15;
      const float bv = bias ? bias[n] : 0.0f;
      if constexpr (EPI == EPI_VT) {
        // out bf16 [B][H][DK][SEQ]; m -> (b, s), n -> (h, d)
        const int bb = mb >> 11, ss = mb & (SEQ - 1);
        const int hh = n >> 7, dd = n & (DK - 1);
        short4v pk;
#pragma unroll
        for (int r = 0; r < 4; ++r) pk[r] = (short)f2bf(acc[fi][fj][r] + bv);
        __hip_bfloat16* o = (__hip_bfloat16*)outv;
        *(short4v*)(o + ((size_t)((bb * NUM_HEADS + hh) * DK + dd)) * SEQ + ss) = pk;
      } else {
#pragma unroll
        for (int r = 0; r < 4; ++r) {
          const int m = mb + r;
          const float v = acc[fi][fj][r] + bv;
          if constexpr (EPI == EPI_BF16) {
            ((__hip_bfloat16*)outv)[(size_t)m * N + n] = __float2bfloat16(v);
          } else if constexpr (EPI == EPI_GELU) {
            const float ge = 0.5f * v * (1.0f + erff(v * 0.70710678118654752f));
            ((__hip_bfloat16*)outv)[(size_t)m * N + n] = __float2bfloat16(ge);
          } else {  // EPI_RESID (resid may alias outv: same-element read->write)
            ((float*)outv)[(size_t)m * N + n] = resid[(size_t)m * N + n] + v;
          }
        }
      }
    }
  }
}

// ---------------------------------------------------------------------------
// Flash attention (causal). Grid: (SEQ/128, B*H). 8 waves, 16 q-rows each
// (128 q-rows per block). LDS 64KB -> 2 blocks/CU (16 waves/CU).
// Q [B,S,H*dk], K [B,S,H*dk], V^T [B,H,dk,S], O [B,S,H*dk] (all bf16)
// ---------------------------------------------------------------------------
__global__ __launch_bounds__(512, 4) void attn_kernel(
    const __hip_bfloat16* __restrict__ Qm, const __hip_bfloat16* __restrict__ Km,
    const __hip_bfloat16* __restrict__ Vt, __hip_bfloat16* __restrict__ Om) {
  __shared__ __align__(16) unsigned char Kl[16384];  // [64 t][128 d] swizzled
  __shared__ __align__(16) unsigned char Vl[16384];  // [128 d][64 t] swizzled
  __shared__ __align__(16) unsigned char Pl[32768];  // per-wave 4KB f32 [16 q][64 t]
  const int tid = threadIdx.x;
  const int lane = tid & 63, w = tid >> 6;  // w in 0..7
  const int l15 = lane & 15, lg = lane >> 4;
  const int bh = blockIdx.y, b = bh >> 4, h = bh & 15;
  const int q0 = blockIdx.x * 128;
  const int qw = q0 + w * 16;
  const int row8 = lane >> 3;

  // Q fragments (A-operand): row = l15, k = ks*32 + lg*8 .. +8
  short8 qf[4];
  const __hip_bfloat16* qbase = Qm + (size_t)(b * SEQ + qw + l15) * D_MODEL + h * DK;
#pragma unroll
  for (int ks = 0; ks < 4; ++ks) qf[ks] = *(const short8*)(qbase + ks * 32 + lg * 8);

  float m_run[4], l_run[4];
  f32x4 acc_o[8];
#pragma unroll
  for (int r = 0; r < 4; ++r) { m_run[r] = -1e30f; l_run[r] = 0.0f; }
#pragma unroll
  for (int fd = 0; fd < 8; ++fd) acc_o[fd] = (f32x4){0.f, 0.f, 0.f, 0.f};

  for (int t0 = 0; t0 < q0 + 128; t0 += 64) {
    // stage K tile: 64 rows x 256B = 16 chunks of 1KB (4 rows); 2 chunks/wave
#pragma unroll
    for (int i = 0; i < 2; ++i) {
      const int c = w * 2 + i;
      const int row = c * 4 + lg;
      const int gcb = l15 ^ (row & 7);
      GLOAD16(Km + (size_t)(b * SEQ + t0 + row) * D_MODEL + h * DK + gcb * 8,
              Kl + c * 1024);
    }
    // stage V^T tile: 128 rows x 128B = 16 chunks of 1KB (8 rows); 2 chunks/wave
#pragma unroll
    for (int i = 0; i < 2; ++i) {
      const int c = w * 2 + i;
      const int row = c * 8 + row8;
      const int gcb = (lane & 7) ^ (row & 7);
      GLOAD16(Vt + (size_t)(bh * DK + row) * SEQ + t0 + gcb * 8, Vl + c * 1024);
    }
    __syncthreads();
    if (t0 <= qw + 15) {
      // S = Q K^T  (output: row q = lg*4+r, col key = l15 within frag fn)
      f32x4 sacc[4];
#pragma unroll
      for (int fn = 0; fn < 4; ++fn) sacc[fn] = (f32x4){0.f, 0.f, 0.f, 0.f};
#pragma unroll
      for (int ks = 0; ks < 4; ++ks) {
        const int cb = ks * 4 + lg;
#pragma unroll
        for (int fn = 0; fn < 4; ++fn) {
          const int rn = fn * 16 + l15;
          short8 kf = *(const short8*)(Kl + rn * 256 + ((cb ^ (rn & 7)) << 4));
          sacc[fn] = MFMA16(qf[ks], kf, sacc[fn]);
        }
      }
      const float scale = 0.088388347648318447f;  // 1/sqrt(128)
      float mt[4] = {-1e30f, -1e30f, -1e30f, -1e30f};
#pragma unroll
      for (int fn = 0; fn < 4; ++fn) {
        const int key = t0 + fn * 16 + l15;
#pragma unroll
        for (int r = 0; r < 4; ++r) {
          const int qg = qw + lg * 4 + r;
          float sv = sacc[fn][r] * scale;
          sv = (key <= qg) ? sv : -1e30f;
          sacc[fn][r] = sv;
          mt[r] = fmaxf(mt[r], sv);
        }
      }
      float alpha[4], ls[4];
#pragma unroll
      for (int r = 0; r < 4; ++r) {
#pragma unroll
        for (int off = 1; off < 16; off <<= 1) mt[r] = fmaxf(mt[r], __shfl_xor(mt[r], off));
        const float mnew = fmaxf(m_run[r], mt[r]);
        alpha[r] = __expf(m_run[r] - mnew);
        m_run[r] = mnew;
        ls[r] = 0.0f;
      }
#pragma unroll
      for (int fn = 0; fn < 4; ++fn)
#pragma unroll
        for (int r = 0; r < 4; ++r) {
          const float p = __expf(sacc[fn][r] - m_run[r]);
          sacc[fn][r] = p;
          ls[r] += p;
        }
#pragma unroll
      for (int r = 0; r < 4; ++r) {
#pragma unroll
        for (int off = 1; off < 16; off <<= 1) ls[r] += __shfl_xor(ls[r], off);
        l_run[r] = l_run[r] * alpha[r] + ls[r];
      }
#pragma unroll
      for (int fd = 0; fd < 8; ++fd)
#pragma unroll
        for (int r = 0; r < 4; ++r) acc_o[fd][r] *= alpha[r];
      // write P (f32) to wave-local LDS, swizzled: slot = (t>>3) ^ (q&7)
      unsigned char* pw = Pl + w * 4096;
#pragma unroll
      for (int fn = 0; fn < 4; ++fn) {
        const int t = fn * 16 + l15;
#pragma unroll
        for (int r = 0; r < 4; ++r) {
          const int qq = lg * 4 + r;
          *(float*)(pw + qq * 256 + (((t >> 3) ^ (qq & 7)) << 5) + (t & 7) * 4) =
              sacc[fn][r];
        }
      }
      // O += P V  (A-operand P: row q = l15, k t = ks*32 + lg*8)
#pragma unroll
      for (int ks = 0; ks < 2; ++ks) {
        const int cb = ks * 4 + lg;
        const int qq = l15;
        const float4* pp =
            (const float4*)(pw + qq * 256 + ((cb ^ (qq & 7)) << 5));
        const float4 pa = pp[0], pb = pp[1];
        short8 pf;
        pf[0] = (short)f2bf(pa.x); pf[1] = (short)f2bf(pa.y);
        pf[2] = (short)f2bf(pa.z); pf[3] = (short)f2bf(pa.w);
        pf[4] = (short)f2bf(pb.x); pf[5] = (short)f2bf(pb.y);
        pf[6] = (short)f2bf(pb.z); pf[7] = (short)f2bf(pb.w);
#pragma unroll
        for (int fd = 0; fd < 8; ++fd) {
          const int rv = fd * 16 + l15;
          short8 vf = *(const short8*)(Vl + rv * 128 + ((cb ^ (rv & 7)) << 4));
          acc_o[fd] = MFMA16(pf, vf, acc_o[fd]);
        }
      }
    }
    __syncthreads();
  }
#pragma unroll
  for (int r = 0; r < 4; ++r) {
    const float inv = 1.0f / l_run[r];
    const int qg = qw + lg * 4 + r;
    __hip_bfloat16* ob = Om + (size_t)(b * SEQ + qg) * D_MODEL + h * DK + l15;
#pragma unroll
    for (int fd = 0; fd < 8; ++fd)
      ob[fd * 16] = __float2bfloat16(acc_o[fd][r] * inv);
  }
}

// ---------------------------------------------------------------------------
// Workspace layout (192 MiB peak, time-shared):
//   @0   Hb   (32M)  LN1 out -> later LN2 out
//   @32  Q    (32M)  -> after attn: W1T (32M)
//   @64  K    (32M)  -> after attn: W2T (32M)
//   @96  Vt   (32M)  -\
//   @128 AO   (32M)  --> after O-proj: FF1 chunk (64M, 4096x8192 bf16)
//   @160 WqT(8) WkT(8) WvT(8) WoT(8)
// X2 (f32 residual stream) lives in d_out itself.
// ---------------------------------------------------------------------------
extern "C" void kernel_launch(void* const* d_in, const int* in_sizes, int n_in,
                              void* d_out, int out_size, void* d_ws, size_t ws_size,
                              hipStream_t stream) {
  (void)in_sizes; (void)n_in; (void)out_size;
  const size_t MB = 1024 * 1024;
  if (ws_size < 192 * MB) return;  // diagnostic guard: clean absmax-fail, not a fault

  const float* x  = (const float*)d_in[0];
  const float* Wq = (const float*)d_in[1];
  const float* bq = (const float*)d_in[2];
  const float* Wk = (const float*)d_in[3];
  const float* bk = (const float*)d_in[4];
  const float* Wv = (const float*)d_in[5];
  const float* bv = (const float*)d_in[6];
  const float* Wo = (const float*)d_in[7];
  const float* bo = (const float*)d_in[8];
  const float* W1 = (const float*)d_in[9];
  const float* b1 = (const float*)d_in[10];
  const float* W2 = (const float*)d_in[11];
  const float* b2 = (const float*)d_in[12];
  const float* g1 = (const float*)d_in[13];
  const float* be1 = (const float*)d_in[14];
  const float* g2 = (const float*)d_in[15];
  const float* be2 = (const float*)d_in[16];

  char* ws = (char*)d_ws;
  __hip_bfloat16* Hb  = (__hip_bfloat16*)(ws + 0 * MB);
  __hip_bfloat16* Qb  = (__hip_bfloat16*)(ws + 32 * MB);
  __hip_bfloat16* Kb  = (__hip_bfloat16*)(ws + 64 * MB);
  __hip_bfloat16* Vtb = (__hip_bfloat16*)(ws + 96 * MB);
  __hip_bfloat16* AOb = (__hip_bfloat16*)(ws + 128 * MB);
  __hip_bfloat16* W1T = (__hip_bfloat16*)(ws + 32 * MB);   // after attn
  __hip_bfloat16* W2T = (__hip_bfloat16*)(ws + 64 * MB);   // after attn
  __hip_bfloat16* FF1 = (__hip_bfloat16*)(ws + 96 * MB);   // after O-proj
  __hip_bfloat16* WqT = (__hip_bfloat16*)(ws + 160 * MB);
  __hip_bfloat16* WkT = (__hip_bfloat16*)(ws + 168 * MB);
  __hip_bfloat16* WvT = (__hip_bfloat16*)(ws + 176 * MB);
  __hip_bfloat16* WoT = (__hip_bfloat16*)(ws + 184 * MB);
  float* X2 = (float*)d_out;  // residual stream lives in d_out

  const dim3 tb(256);
  // small weight converts (f32 [K][N] -> bf16 [N][K])
  transpose_cvt_kernel<<<dim3(64, 64), tb, 0, stream>>>(Wq, WqT, 2048, 2048);
  transpose_cvt_kernel<<<dim3(64, 64), tb, 0, stream>>>(Wk, WkT, 2048, 2048);
  transpose_cvt_kernel<<<dim3(64, 64), tb, 0, stream>>>(Wv, WvT, 2048, 2048);
  transpose_cvt_kernel<<<dim3(64, 64), tb, 0, stream>>>(Wo, WoT, 2048, 2048);

  layernorm_kernel<<<MTOT, tb, 0, stream>>>(x, g1, be1, Hb);

  // QKV/O: M=8192 (nby=32), N=2048 (nbx=8) -> 256 blocks
  gemm_kernel<EPI_BF16><<<256, 512, 0, stream>>>(Hb, WqT, bq, nullptr, Qb, MTOT, 2048, 2048, 32);
  gemm_kernel<EPI_BF16><<<256, 512, 0, stream>>>(Hb, WkT, bk, nullptr, Kb, MTOT, 2048, 2048, 32);
  gemm_kernel<EPI_VT><<<256, 512, 0, stream>>>(Hb, WvT, bv, nullptr, Vtb, MTOT, 2048, 2048, 32);

  attn_kernel<<<dim3(SEQ / 128, BATCH * NUM_HEADS), dim3(512), 0, stream>>>(Qb, Kb, Vtb, AOb);

  // Q/K regions now dead -> convert FFN weights into them
  transpose_cvt_kernel<<<dim3(256, 64), tb, 0, stream>>>(W1, W1T, 2048, 8192);
  transpose_cvt_kernel<<<dim3(64, 256), tb, 0, stream>>>(W2, W2T, 8192, 2048);

  // O-proj + residual -> X2 (= d_out, f32)
  gemm_kernel<EPI_RESID><<<256, 512, 0, stream>>>(AOb, WoT, bo, x, X2, MTOT, 2048, 2048, 32);

  layernorm_kernel<<<MTOT, tb, 0, stream>>>(X2, g2, be2, Hb);

  // FFN in 2 chunks of 4096 rows (FF1 chunk reuses Vt+AO regions, 64 MiB)
  for (int c = 0; c < 2; ++c) {
    const size_t moff = (size_t)c * 4096;
    // FF1 chunk: M=4096 (nby=16), N=8192 (nbx=32) -> 512 blocks
    gemm_kernel<EPI_GELU><<<512, 512, 0, stream>>>(
        Hb + moff * D_MODEL, W1T, b1, nullptr, FF1, 4096, 8192, 2048, 16);
    // FF2 chunk: M=4096 (nby=16), N=2048 (nbx=8) -> 128 blocks
    gemm_kernel<EPI_RESID><<<128, 512, 0, stream>>>(
        FF1, W2T, b2, X2 + moff * D_MODEL, X2 + moff * D_MODEL, 4096, 2048, 8192, 16);
  }
}

// Round 6
// 1376.233 us; speedup vs baseline: 1.1045x; 1.1045x over previous
//
#include <hip/hip_runtime.h>
#include <hip/hip_bf16.h>

#define D_MODEL 2048
#define NUM_HEADS 16
#define D_FF 8192
#define BATCH 4
#define SEQ 2048
#define DK 128
#define MTOT (BATCH * SEQ)  // 8192

typedef __attribute__((ext_vector_type(8))) short short8;
typedef __attribute__((ext_vector_type(4))) short short4v;
typedef __attribute__((ext_vector_type(4))) float f32x4;

#define MFMA16(a, b, c) __builtin_amdgcn_mfma_f32_16x16x32_bf16(a, b, c, 0, 0, 0)

#define GLOAD16(gp, lp)                                                        \
  __builtin_amdgcn_global_load_lds(                                            \
      (const __attribute__((address_space(1))) void*)(gp),                     \
      (__attribute__((address_space(3))) void*)(lp), 16, 0, 0)

static __device__ __forceinline__ unsigned short f2bf(float f) {
  return __builtin_bit_cast(unsigned short, __float2bfloat16(f));
}

// ---------------------------------------------------------------------------
// Weight convert + transpose: in f32 [K][N] -> out bf16 [N][K]
// ---------------------------------------------------------------------------
__global__ __launch_bounds__(256) void transpose_cvt_kernel(
    const float* __restrict__ in, __hip_bfloat16* __restrict__ out, int K, int N) {
  __shared__ float tile[32][33];
  const int n0 = blockIdx.x * 32, k0 = blockIdx.y * 32;
  const int tx = threadIdx.x & 31, ty = threadIdx.x >> 5;  // 32 x 8
#pragma unroll
  for (int i = 0; i < 4; ++i)
    tile[ty + i * 8][tx] = in[(size_t)(k0 + ty + i * 8) * N + n0 + tx];
  __syncthreads();
#pragma unroll
  for (int i = 0; i < 4; ++i)
    out[(size_t)(n0 + ty + i * 8) * K + k0 + tx] = __float2bfloat16(tile[tx][ty + i * 8]);
}

// ---------------------------------------------------------------------------
// LayerNorm: f32 [M][D_MODEL] -> bf16 [M][D_MODEL]
// ---------------------------------------------------------------------------
__global__ __launch_bounds__(256) void layernorm_kernel(
    const float* __restrict__ x, const float* __restrict__ g,
    const float* __restrict__ bta, __hip_bfloat16* __restrict__ out) {
  const int row = blockIdx.x;
  const int tid = threadIdx.x;
  const float* xr = x + (size_t)row * D_MODEL;
  float4 v0 = *(const float4*)(xr + tid * 8);
  float4 v1 = *(const float4*)(xr + tid * 8 + 4);
  float s = v0.x + v0.y + v0.z + v0.w + v1.x + v1.y + v1.z + v1.w;
  float q = v0.x * v0.x + v0.y * v0.y + v0.z * v0.z + v0.w * v0.w +
            v1.x * v1.x + v1.y * v1.y + v1.z * v1.z + v1.w * v1.w;
#pragma unroll
  for (int off = 1; off < 64; off <<= 1) {
    s += __shfl_xor(s, off);
    q += __shfl_xor(q, off);
  }
  __shared__ float rs[4], rq[4];
  if ((tid & 63) == 0) {
    rs[tid >> 6] = s;
    rq[tid >> 6] = q;
  }
  __syncthreads();
  s = rs[0] + rs[1] + rs[2] + rs[3];
  q = rq[0] + rq[1] + rq[2] + rq[3];
  const float mu = s * (1.0f / D_MODEL);
  const float var = q * (1.0f / D_MODEL) - mu * mu;
  const float rstd = rsqrtf(var + 1e-5f);
  float4 g0 = *(const float4*)(g + tid * 8);
  float4 g1 = *(const float4*)(g + tid * 8 + 4);
  float4 b0 = *(const float4*)(bta + tid * 8);
  float4 b1 = *(const float4*)(bta + tid * 8 + 4);
  short8 o;
  o[0] = (short)f2bf((v0.x - mu) * rstd * g0.x + b0.x);
  o[1] = (short)f2bf((v0.y - mu) * rstd * g0.y + b0.y);
  o[2] = (short)f2bf((v0.z - mu) * rstd * g0.z + b0.z);
  o[3] = (short)f2bf((v0.w - mu) * rstd * g0.w + b0.w);
  o[4] = (short)f2bf((v1.x - mu) * rstd * g1.x + b1.x);
  o[5] = (short)f2bf((v1.y - mu) * rstd * g1.y + b1.y);
  o[6] = (short)f2bf((v1.z - mu) * rstd * g1.z + b1.z);
  o[7] = (short)f2bf((v1.w - mu) * rstd * g1.w + b1.w);
  *(short8*)(out + (size_t)row * D_MODEL + tid * 8) = o;
}

// ---------------------------------------------------------------------------
// GEMM: C[M][N] = A[M][K] @ Bt[N][K]^T (+bias, epilogue variants)
// 128x128 tile, BK=64, 4 waves (2x2), mfma 16x16x32 bf16.  (round-4 version)
// ---------------------------------------------------------------------------
enum { EPI_BF16 = 0, EPI_VT = 1, EPI_RESID = 2, EPI_GELU = 3 };

template <int EPI>
__global__ __launch_bounds__(256, 2) void gemm_kernel(
    const __hip_bfloat16* __restrict__ A, const __hip_bfloat16* __restrict__ Bt,
    const float* __restrict__ bias, const float* __restrict__ resid,
    void* __restrict__ outv, int M, int N, int K) {
  __shared__ __align__(16) unsigned char sA[16384];
  __shared__ __align__(16) unsigned char sB[16384];
  const int tid = threadIdx.x;
  const int lane = tid & 63, w = tid >> 6;
  const int l15 = lane & 15, lg = lane >> 4;
  const int m0 = blockIdx.y * 128, n0 = blockIdx.x * 128;
  const int wm = (w >> 1) * 64, wn = (w & 1) * 64;

  f32x4 acc[4][4] = {};

  const int row8 = lane >> 3;        // 0..7 (row within 8-row chunk)
  const int g8 = (lane & 7) ^ row8;  // pre-swizzled source col16-block

  for (int kt = 0; kt < K; kt += 64) {
#pragma unroll
    for (int i = 0; i < 4; ++i) {
      const int c = w * 4 + i;  // chunk 0..15, 8 rows of 128B each
      const int row = c * 8 + row8;
      GLOAD16(A + (size_t)(m0 + row) * K + kt + g8 * 8, sA + c * 1024);
      GLOAD16(Bt + (size_t)(n0 + row) * K + kt + g8 * 8, sB + c * 1024);
    }
    __syncthreads();
#pragma unroll
    for (int ks = 0; ks < 2; ++ks) {
      const int cb = ks * 4 + lg;
      short8 af[4], bf[4];
#pragma unroll
      for (int f = 0; f < 4; ++f) {
        const int ra = wm + f * 16 + l15;
        af[f] = *(const short8*)(sA + ra * 128 + ((cb ^ (ra & 7)) << 4));
        const int rb = wn + f * 16 + l15;
        bf[f] = *(const short8*)(sB + rb * 128 + ((cb ^ (rb & 7)) << 4));
      }
#pragma unroll
      for (int fi = 0; fi < 4; ++fi)
#pragma unroll
        for (int fj = 0; fj < 4; ++fj)
          acc[fi][fj] = MFMA16(af[fi], bf[fj], acc[fi][fj]);
    }
    __syncthreads();
  }

#pragma unroll
  for (int fi = 0; fi < 4; ++fi) {
#pragma unroll
    for (int fj = 0; fj < 4; ++fj) {
      const int mb = m0 + wm + fi * 16 + lg * 4;
      const int n = n0 + wn + fj * 16 + l15;
      const float bv = bias ? bias[n] : 0.0f;
      if constexpr (EPI == EPI_VT) {
        // out bf16 [B][H][DK][SEQ]; m -> (b, s), n -> (h, d)
        const int bb = mb >> 11, ss = mb & (SEQ - 1);
        const int hh = n >> 7, dd = n & (DK - 1);
        short4v pk;
#pragma unroll
        for (int r = 0; r < 4; ++r) pk[r] = (short)f2bf(acc[fi][fj][r] + bv);
        __hip_bfloat16* o = (__hip_bfloat16*)outv;
        *(short4v*)(o + ((size_t)((bb * NUM_HEADS + hh) * DK + dd)) * SEQ + ss) = pk;
      } else {
#pragma unroll
        for (int r = 0; r < 4; ++r) {
          const int m = mb + r;
          const float v = acc[fi][fj][r] + bv;
          if constexpr (EPI == EPI_BF16) {
            ((__hip_bfloat16*)outv)[(size_t)m * N + n] = __float2bfloat16(v);
          } else if constexpr (EPI == EPI_GELU) {
            const float ge = 0.5f * v * (1.0f + erff(v * 0.70710678118654752f));
            ((__hip_bfloat16*)outv)[(size_t)m * N + n] = __float2bfloat16(ge);
          } else {  // EPI_RESID (resid may alias outv: same-element read->write)
            ((float*)outv)[(size_t)m * N + n] = resid[(size_t)m * N + n] + v;
          }
        }
      }
    }
  }
}

// ---------------------------------------------------------------------------
// Flash attention (causal). Grid: (SEQ/128, B*H). 8 waves, 16 q-rows each.
// Double-buffered K/V with stage-ahead + counted vmcnt(4) (T3/T4 minimum):
// tile t+1's global_load_lds stay in flight across tile t's compute; never
// drain vmcnt to 0 in the loop. P-scratch is bf16 (16KB). LDS total 80KB ->
// 2 blocks/CU.  Q [B,S,H*dk], K [B,S,H*dk], V^T [B,H,dk,S], O [B,S,H*dk].
// ---------------------------------------------------------------------------
__global__ __launch_bounds__(512, 4) void attn_kernel(
    const __hip_bfloat16* __restrict__ Qm, const __hip_bfloat16* __restrict__ Km,
    const __hip_bfloat16* __restrict__ Vt, __hip_bfloat16* __restrict__ Om) {
  __shared__ __align__(16) unsigned char Kl[2][16384];  // [64 t][128 d] swizzled
  __shared__ __align__(16) unsigned char Vl[2][16384];  // [128 d][64 t] swizzled
  __shared__ __align__(16) unsigned char Pl[16384];     // per-wave 2KB bf16 [16 q][64 t]
  const int tid = threadIdx.x;
  const int lane = tid & 63, w = tid >> 6;  // w in 0..7
  const int l15 = lane & 15, lg = lane >> 4;
  const int bh = blockIdx.y, b = bh >> 4, h = bh & 15;
  const int q0 = blockIdx.x * 128;
  const int qw = q0 + w * 16;
  const int row8 = lane >> 3;
  const int nt = (q0 >> 6) + 2;  // K/V tiles 0 .. q0/64+1

  // Q fragments (A-operand): row = l15, k = ks*32 + lg*8 .. +8
  short8 qf[4];
  const __hip_bfloat16* qbase = Qm + (size_t)(b * SEQ + qw + l15) * D_MODEL + h * DK;
#pragma unroll
  for (int ks = 0; ks < 4; ++ks) qf[ks] = *(const short8*)(qbase + ks * 32 + lg * 8);

  float m_run[4], l_run[4];
  f32x4 acc_o[8];
#pragma unroll
  for (int r = 0; r < 4; ++r) { m_run[r] = -1e30f; l_run[r] = 0.0f; }
#pragma unroll
  for (int fd = 0; fd < 8; ++fd) acc_o[fd] = (f32x4){0.f, 0.f, 0.f, 0.f};

  auto STAGE = [&](int tt) {
    unsigned char* kb = Kl[tt & 1];
    unsigned char* vb = Vl[tt & 1];
    const int t0 = tt * 64;
    // K tile: 64 rows x 256B = 16 chunks of 1KB (4 rows); 2 chunks/wave
#pragma unroll
    for (int i = 0; i < 2; ++i) {
      const int c = w * 2 + i;
      const int row = c * 4 + lg;
      const int gcb = l15 ^ (row & 7);
      GLOAD16(Km + (size_t)(b * SEQ + t0 + row) * D_MODEL + h * DK + gcb * 8,
              kb + c * 1024);
    }
    // V^T tile: 128 rows x 128B = 16 chunks of 1KB (8 rows); 2 chunks/wave
#pragma unroll
    for (int i = 0; i < 2; ++i) {
      const int c = w * 2 + i;
      const int row = c * 8 + row8;
      const int gcb = (lane & 7) ^ (row & 7);
      GLOAD16(Vt + (size_t)(bh * DK + row) * SEQ + t0 + gcb * 8, vb + c * 1024);
    }
  };

  STAGE(0);
  for (int t = 0; t < nt; ++t) {
    const int t0 = t * 64;
    if (t + 1 < nt) {
      STAGE(t + 1);  // 4 loads -> in flight across this tile's compute
      asm volatile("s_waitcnt vmcnt(4)" ::: "memory");  // tile t complete
    } else {
      asm volatile("s_waitcnt vmcnt(0)" ::: "memory");
    }
    __builtin_amdgcn_s_barrier();  // all waves: tile t in LDS; t-1 reads done
    asm volatile("" ::: "memory");
    if (t0 <= qw + 15) {
      const unsigned char* kb = Kl[t & 1];
      const unsigned char* vb = Vl[t & 1];
      // S = Q K^T  (output: row q = lg*4+r, col key = l15 within frag fn)
      f32x4 sacc[4];
#pragma unroll
      for (int fn = 0; fn < 4; ++fn) sacc[fn] = (f32x4){0.f, 0.f, 0.f, 0.f};
#pragma unroll
      for (int ks = 0; ks < 4; ++ks) {
        const int cb = ks * 4 + lg;
#pragma unroll
        for (int fn = 0; fn < 4; ++fn) {
          const int rn = fn * 16 + l15;
          short8 kf = *(const short8*)(kb + rn * 256 + ((cb ^ (rn & 7)) << 4));
          sacc[fn] = MFMA16(qf[ks], kf, sacc[fn]);
        }
      }
      const float scale = 0.088388347648318447f;  // 1/sqrt(128)
      float mt[4] = {-1e30f, -1e30f, -1e30f, -1e30f};
#pragma unroll
      for (int fn = 0; fn < 4; ++fn) {
        const int key = t0 + fn * 16 + l15;
#pragma unroll
        for (int r = 0; r < 4; ++r) {
          const int qg = qw + lg * 4 + r;
          float sv = sacc[fn][r] * scale;
          sv = (key <= qg) ? sv : -1e30f;
          sacc[fn][r] = sv;
          mt[r] = fmaxf(mt[r], sv);
        }
      }
      float alpha[4], ls[4];
#pragma unroll
      for (int r = 0; r < 4; ++r) {
#pragma unroll
        for (int off = 1; off < 16; off <<= 1) mt[r] = fmaxf(mt[r], __shfl_xor(mt[r], off));
        const float mnew = fmaxf(m_run[r], mt[r]);
        alpha[r] = __expf(m_run[r] - mnew);
        m_run[r] = mnew;
        ls[r] = 0.0f;
      }
#pragma unroll
      for (int fn = 0; fn < 4; ++fn)
#pragma unroll
        for (int r = 0; r < 4; ++r) {
          const float p = __expf(sacc[fn][r] - m_run[r]);
          sacc[fn][r] = p;
          ls[r] += p;
        }
#pragma unroll
      for (int r = 0; r < 4; ++r) {
#pragma unroll
        for (int off = 1; off < 16; off <<= 1) ls[r] += __shfl_xor(ls[r], off);
        l_run[r] = l_run[r] * alpha[r] + ls[r];
      }
#pragma unroll
      for (int fd = 0; fd < 8; ++fd)
#pragma unroll
        for (int r = 0; r < 4; ++r) acc_o[fd][r] *= alpha[r];
      // write P (bf16) to wave-local LDS: row q (128B), 16B slot = (t>>3)^(q&7)
      unsigned char* pw = Pl + w * 2048;
#pragma unroll
      for (int fn = 0; fn < 4; ++fn) {
        const int tt = fn * 16 + l15;
#pragma unroll
        for (int r = 0; r < 4; ++r) {
          const int qq = lg * 4 + r;
          *(unsigned short*)(pw + qq * 128 + (((tt >> 3) ^ (qq & 7)) << 4) +
                             (tt & 7) * 2) = f2bf(sacc[fn][r]);
        }
      }
      // O += P V  (A-operand P: row q = l15, k-slot tb = ks*4+lg)
#pragma unroll
      for (int ks = 0; ks < 2; ++ks) {
#pragma unroll
        for (int half = 0; half < 2; ++half) {
          const int tb = (ks * 2 + half) * 2 + (lg & 1) + (lg >> 1) * 0;  // placeholder
        }
        const int tb = ks * 4 + lg;
        short8 pf = *(const short8*)(Pl + w * 2048 + l15 * 128 +
                                     ((tb ^ (l15 & 7)) << 4));
        const int cb = ks * 4 + lg;
#pragma unroll
        for (int fd = 0; fd < 8; ++fd) {
          const int rv = fd * 16 + l15;
          short8 vf = *(const short8*)(vb + rv * 128 + ((cb ^ (rv & 7)) << 4));
          acc_o[fd] = MFMA16(pf, vf, acc_o[fd]);
        }
      }
    }
    asm volatile("" ::: "memory");
    __builtin_amdgcn_s_barrier();  // all reads of buf[t&1] done before t+2 stages it
    asm volatile("" ::: "memory");
  }
#pragma unroll
  for (int r = 0; r < 4; ++r) {
    const float inv = 1.0f / l_run[r];
    const int qg = qw + lg * 4 + r;
    __hip_bfloat16* ob = Om + (size_t)(b * SEQ + qg) * D_MODEL + h * DK + l15;
#pragma unroll
    for (int fd = 0; fd < 8; ++fd)
      ob[fd * 16] = __float2bfloat16(acc_o[fd][r] * inv);
  }
}

// ---------------------------------------------------------------------------
// Workspace layout (192 MiB peak, time-shared):
//   @0   Hb   (32M)  LN1 out -> later LN2 out
//   @32  Q    (32M)  -> after attn: W1T (32M)
//   @64  K    (32M)  -> after attn: W2T (32M)
//   @96  Vt   (32M)  -\
//   @128 AO   (32M)  --> after O-proj: FF1 chunk (64M, 4096x8192 bf16)
//   @160 WqT(8) WkT(8) WvT(8) WoT(8)
// X2 (f32 residual stream) lives in d_out itself.
// ---------------------------------------------------------------------------
extern "C" void kernel_launch(void* const* d_in, const int* in_sizes, int n_in,
                              void* d_out, int out_size, void* d_ws, size_t ws_size,
                              hipStream_t stream) {
  (void)in_sizes; (void)n_in; (void)out_size;
  const size_t MB = 1024 * 1024;
  if (ws_size < 192 * MB) return;  // diagnostic guard: clean absmax-fail, not a fault

  const float* x  = (const float*)d_in[0];
  const float* Wq = (const float*)d_in[1];
  const float* bq = (const float*)d_in[2];
  const float* Wk = (const float*)d_in[3];
  const float* bk = (const float*)d_in[4];
  const float* Wv = (const float*)d_in[5];
  const float* bv = (const float*)d_in[6];
  const float* Wo = (const float*)d_in[7];
  const float* bo = (const float*)d_in[8];
  const float* W1 = (const float*)d_in[9];
  const float* b1 = (const float*)d_in[10];
  const float* W2 = (const float*)d_in[11];
  const float* b2 = (const float*)d_in[12];
  const float* g1 = (const float*)d_in[13];
  const float* be1 = (const float*)d_in[14];
  const float* g2 = (const float*)d_in[15];
  const float* be2 = (const float*)d_in[16];

  char* ws = (char*)d_ws;
  __hip_bfloat16* Hb  = (__hip_bfloat16*)(ws + 0 * MB);
  __hip_bfloat16* Qb  = (__hip_bfloat16*)(ws + 32 * MB);
  __hip_bfloat16* Kb  = (__hip_bfloat16*)(ws + 64 * MB);
  __hip_bfloat16* Vtb = (__hip_bfloat16*)(ws + 96 * MB);
  __hip_bfloat16* AOb = (__hip_bfloat16*)(ws + 128 * MB);
  __hip_bfloat16* W1T = (__hip_bfloat16*)(ws + 32 * MB);   // after attn
  __hip_bfloat16* W2T = (__hip_bfloat16*)(ws + 64 * MB);   // after attn
  __hip_bfloat16* FF1 = (__hip_bfloat16*)(ws + 96 * MB);   // after O-proj
  __hip_bfloat16* WqT = (__hip_bfloat16*)(ws + 160 * MB);
  __hip_bfloat16* WkT = (__hip_bfloat16*)(ws + 168 * MB);
  __hip_bfloat16* WvT = (__hip_bfloat16*)(ws + 176 * MB);
  __hip_bfloat16* WoT = (__hip_bfloat16*)(ws + 184 * MB);
  float* X2 = (float*)d_out;  // residual stream lives in d_out

  const dim3 tb(256);
  // small weight converts (f32 [K][N] -> bf16 [N][K])
  transpose_cvt_kernel<<<dim3(64, 64), tb, 0, stream>>>(Wq, WqT, 2048, 2048);
  transpose_cvt_kernel<<<dim3(64, 64), tb, 0, stream>>>(Wk, WkT, 2048, 2048);
  transpose_cvt_kernel<<<dim3(64, 64), tb, 0, stream>>>(Wv, WvT, 2048, 2048);
  transpose_cvt_kernel<<<dim3(64, 64), tb, 0, stream>>>(Wo, WoT, 2048, 2048);

  layernorm_kernel<<<MTOT, tb, 0, stream>>>(x, g1, be1, Hb);

  const dim3 gQKV(2048 / 128, MTOT / 128);
  gemm_kernel<EPI_BF16><<<gQKV, tb, 0, stream>>>(Hb, WqT, bq, nullptr, Qb, MTOT, 2048, 2048);
  gemm_kernel<EPI_BF16><<<gQKV, tb, 0, stream>>>(Hb, WkT, bk, nullptr, Kb, MTOT, 2048, 2048);
  gemm_kernel<EPI_VT><<<gQKV, tb, 0, stream>>>(Hb, WvT, bv, nullptr, Vtb, MTOT, 2048, 2048);

  attn_kernel<<<dim3(SEQ / 128, BATCH * NUM_HEADS), dim3(512), 0, stream>>>(Qb, Kb, Vtb, AOb);

  // Q/K regions now dead -> convert FFN weights into them
  transpose_cvt_kernel<<<dim3(256, 64), tb, 0, stream>>>(W1, W1T, 2048, 8192);
  transpose_cvt_kernel<<<dim3(64, 256), tb, 0, stream>>>(W2, W2T, 8192, 2048);

  // O-proj + residual -> X2 (= d_out, f32)
  gemm_kernel<EPI_RESID><<<gQKV, tb, 0, stream>>>(AOb, WoT, bo, x, X2, MTOT, 2048, 2048);

  layernorm_kernel<<<MTOT, tb, 0, stream>>>(X2, g2, be2, Hb);

  // FFN in 2 chunks of 4096 rows (FF1 chunk reuses Vt+AO regions, 64 MiB)
  for (int c = 0; c < 2; ++c) {
    const size_t moff = (size_t)c * 4096;
    gemm_kernel<EPI_GELU><<<dim3(8192 / 128, 4096 / 128), tb, 0, stream>>>(
        Hb + moff * D_MODEL, W1T, b1, nullptr, FF1, 4096, 8192, 2048);
    gemm_kernel<EPI_RESID><<<dim3(2048 / 128, 4096 / 128), tb, 0, stream>>>(
        FF1, W2T, b2, X2 + moff * D_MODEL, X2 + moff * D_MODEL, 4096, 2048, 8192);
  }
}

// Round 7
// 1348.168 us; speedup vs baseline: 1.1275x; 1.0208x over previous
//
#include <hip/hip_runtime.h>
#include <hip/hip_bf16.h>

#define D_MODEL 2048
#define NUM_HEADS 16
#define D_FF 8192
#define BATCH 4
#define SEQ 2048
#define DK 128
#define MTOT (BATCH * SEQ)  // 8192

typedef __attribute__((ext_vector_type(8))) short short8;
typedef __attribute__((ext_vector_type(4))) short short4v;
typedef __attribute__((ext_vector_type(4))) float f32x4;

#define MFMA16(a, b, c) __builtin_amdgcn_mfma_f32_16x16x32_bf16(a, b, c, 0, 0, 0)

#define GLOAD16(gp, lp)                                                        \
  __builtin_amdgcn_global_load_lds(                                            \
      (const __attribute__((address_space(1))) void*)(gp),                     \
      (__attribute__((address_space(3))) void*)(lp), 16, 0, 0)

static __device__ __forceinline__ unsigned short f2bf(float f) {
  return __builtin_bit_cast(unsigned short, __float2bfloat16(f));
}

// ---------------------------------------------------------------------------
// Weight convert + transpose: in f32 [K][N] -> out bf16 [N][K]
// ---------------------------------------------------------------------------
__global__ __launch_bounds__(256) void transpose_cvt_kernel(
    const float* __restrict__ in, __hip_bfloat16* __restrict__ out, int K, int N) {
  __shared__ float tile[32][33];
  const int n0 = blockIdx.x * 32, k0 = blockIdx.y * 32;
  const int tx = threadIdx.x & 31, ty = threadIdx.x >> 5;  // 32 x 8
#pragma unroll
  for (int i = 0; i < 4; ++i)
    tile[ty + i * 8][tx] = in[(size_t)(k0 + ty + i * 8) * N + n0 + tx];
  __syncthreads();
#pragma unroll
  for (int i = 0; i < 4; ++i)
    out[(size_t)(n0 + ty + i * 8) * K + k0 + tx] = __float2bfloat16(tile[tx][ty + i * 8]);
}

// ---------------------------------------------------------------------------
// LayerNorm: f32 [M][D_MODEL] -> bf16 [M][D_MODEL]
// ---------------------------------------------------------------------------
__global__ __launch_bounds__(256) void layernorm_kernel(
    const float* __restrict__ x, const float* __restrict__ g,
    const float* __restrict__ bta, __hip_bfloat16* __restrict__ out) {
  const int row = blockIdx.x;
  const int tid = threadIdx.x;
  const float* xr = x + (size_t)row * D_MODEL;
  float4 v0 = *(const float4*)(xr + tid * 8);
  float4 v1 = *(const float4*)(xr + tid * 8 + 4);
  float s = v0.x + v0.y + v0.z + v0.w + v1.x + v1.y + v1.z + v1.w;
  float q = v0.x * v0.x + v0.y * v0.y + v0.z * v0.z + v0.w * v0.w +
            v1.x * v1.x + v1.y * v1.y + v1.z * v1.z + v1.w * v1.w;
#pragma unroll
  for (int off = 1; off < 64; off <<= 1) {
    s += __shfl_xor(s, off);
    q += __shfl_xor(q, off);
  }
  __shared__ float rs[4], rq[4];
  if ((tid & 63) == 0) {
    rs[tid >> 6] = s;
    rq[tid >> 6] = q;
  }
  __syncthreads();
  s = rs[0] + rs[1] + rs[2] + rs[3];
  q = rq[0] + rq[1] + rq[2] + rq[3];
  const float mu = s * (1.0f / D_MODEL);
  const float var = q * (1.0f / D_MODEL) - mu * mu;
  const float rstd = rsqrtf(var + 1e-5f);
  float4 g0 = *(const float4*)(g + tid * 8);
  float4 g1 = *(const float4*)(g + tid * 8 + 4);
  float4 b0 = *(const float4*)(bta + tid * 8);
  float4 b1 = *(const float4*)(bta + tid * 8 + 4);
  short8 o;
  o[0] = (short)f2bf((v0.x - mu) * rstd * g0.x + b0.x);
  o[1] = (short)f2bf((v0.y - mu) * rstd * g0.y + b0.y);
  o[2] = (short)f2bf((v0.z - mu) * rstd * g0.z + b0.z);
  o[3] = (short)f2bf((v0.w - mu) * rstd * g0.w + b0.w);
  o[4] = (short)f2bf((v1.x - mu) * rstd * g1.x + b1.x);
  o[5] = (short)f2bf((v1.y - mu) * rstd * g1.y + b1.y);
  o[6] = (short)f2bf((v1.z - mu) * rstd * g1.z + b1.z);
  o[7] = (short)f2bf((v1.w - mu) * rstd * g1.w + b1.w);
  *(short8*)(out + (size_t)row * D_MODEL + tid * 8) = o;
}

// ---------------------------------------------------------------------------
// GEMM: C[M][N] = A[M][K] @ Bt[N][K]^T (+bias, epilogue variants)
// 256x128 tile, BK=64, 8 waves (4Mx2N), 3-buffer LDS ring (144 KiB).
// Counted-vmcnt pipeline: one s_barrier per K-tile, 2 tiles (12 loads)
// always in flight, vmcnt never drained in the main loop. setprio around
// MFMA. LDS 128B rows, XOR-(row&7) 16B-block swizzle; global source
// pre-swizzled with the same involution (rule #21).
// Race safety: STAGE(t+2) -> buf[(t+2)%3] overwrites tile t-1's buffer;
// every wave's t-1 ds_reads drain before its last t-1 MFMA (compiler
// lgkmcnt), which precedes its arrival at iter-t's barrier; STAGE is
// issued after that barrier.
// ---------------------------------------------------------------------------
enum { EPI_BF16 = 0, EPI_VT = 1, EPI_RESID = 2, EPI_GELU = 3 };

template <int EPI>
__global__ __launch_bounds__(512, 2) void gemm_kernel(
    const __hip_bfloat16* __restrict__ A, const __hip_bfloat16* __restrict__ Bt,
    const float* __restrict__ bias, const float* __restrict__ resid,
    void* __restrict__ outv, int M, int N, int K) {
  __shared__ __align__(16) unsigned char lds[3][49152];  // [ring][A 32K | B 16K]
  const int tid = threadIdx.x;
  const int lane = tid & 63, w = tid >> 6;  // 8 waves
  const int l15 = lane & 15, lg = lane >> 4;
  const int m0 = blockIdx.y * 256, n0 = blockIdx.x * 128;
  const int wm = (w >> 1) * 64, wn = (w & 1) * 64;

  f32x4 acc[4][4] = {};

  const int row8 = lane >> 3;        // 0..7 (row within 8-row chunk)
  const int g8 = (lane & 7) ^ row8;  // pre-swizzled source 16B-block

  auto STAGE = [&](int tt) {
    unsigned char* db = lds[tt % 3];
    const size_t ko = (size_t)tt * 64;
#pragma unroll
    for (int i = 0; i < 4; ++i) {
      const int c = w * 4 + i;  // A chunk 0..31 (8 rows x 128B each)
      const int row = c * 8 + row8;
      GLOAD16(A + (size_t)(m0 + row) * K + ko + g8 * 8, db + c * 1024);
    }
#pragma unroll
    for (int i = 0; i < 2; ++i) {
      const int c = w * 2 + i;  // B chunk 0..15
      const int row = c * 8 + row8;
      GLOAD16(Bt + (size_t)(n0 + row) * K + ko + g8 * 8, db + 32768 + c * 1024);
    }
  };
  auto COMPUTE = [&](int tt) {
    const unsigned char* db = lds[tt % 3];
#pragma unroll
    for (int ks = 0; ks < 2; ++ks) {
      const int cb = ks * 4 + lg;
      short8 af[4], bf[4];
#pragma unroll
      for (int f = 0; f < 4; ++f) {
        const int ra = wm + f * 16 + l15;
        af[f] = *(const short8*)(db + ra * 128 + ((cb ^ (ra & 7)) << 4));
        const int rb = wn + f * 16 + l15;
        bf[f] = *(const short8*)(db + 32768 + rb * 128 + ((cb ^ (rb & 7)) << 4));
      }
      __builtin_amdgcn_s_setprio(1);
#pragma unroll
      for (int fi = 0; fi < 4; ++fi)
#pragma unroll
        for (int fj = 0; fj < 4; ++fj)
          acc[fi][fj] = MFMA16(af[fi], bf[fj], acc[fi][fj]);
      __builtin_amdgcn_s_setprio(0);
    }
  };

  const int nt = K >> 6;  // K-tiles of 64
  STAGE(0);
  STAGE(1);
  for (int t = 0; t < nt; ++t) {
    if (t + 2 < nt) {
      asm volatile("s_waitcnt vmcnt(6)" ::: "memory");  // tile t complete
      __builtin_amdgcn_s_barrier();
      STAGE(t + 2);  // into buffer of tile t-1 (reads drained pre-barrier)
    } else if (t + 2 == nt) {
      asm volatile("s_waitcnt vmcnt(6)" ::: "memory");
      __builtin_amdgcn_s_barrier();
    } else {
      asm volatile("s_waitcnt vmcnt(0)" ::: "memory");
      __builtin_amdgcn_s_barrier();
    }
    COMPUTE(t);
  }

#pragma unroll
  for (int fi = 0; fi < 4; ++fi) {
#pragma unroll
    for (int fj = 0; fj < 4; ++fj) {
      const int mb = m0 + wm + fi * 16 + lg * 4;
      const int n = n0 + wn + fj * 16 + l15;
      const float bv = bias ? bias[n] : 0.0f;
      if constexpr (EPI == EPI_VT) {
        // out bf16 [B][H][DK][SEQ]; m -> (b, s), n -> (h, d)
        const int bb = mb >> 11, ss = mb & (SEQ - 1);
        const int hh = n >> 7, dd = n & (DK - 1);
        short4v pk;
#pragma unroll
        for (int r = 0; r < 4; ++r) pk[r] = (short)f2bf(acc[fi][fj][r] + bv);
        __hip_bfloat16* o = (__hip_bfloat16*)outv;
        *(short4v*)(o + ((size_t)((bb * NUM_HEADS + hh) * DK + dd)) * SEQ + ss) = pk;
      } else {
#pragma unroll
        for (int r = 0; r < 4; ++r) {
          const int m = mb + r;
          const float v = acc[fi][fj][r] + bv;
          if constexpr (EPI == EPI_BF16) {
            ((__hip_bfloat16*)outv)[(size_t)m * N + n] = __float2bfloat16(v);
          } else if constexpr (EPI == EPI_GELU) {
            const float ge = 0.5f * v * (1.0f + erff(v * 0.70710678118654752f));
            ((__hip_bfloat16*)outv)[(size_t)m * N + n] = __float2bfloat16(ge);
          } else {  // EPI_RESID (resid may alias outv: same-element read->write)
            ((float*)outv)[(size_t)m * N + n] = resid[(size_t)m * N + n] + v;
          }
        }
      }
    }
  }
}

// ---------------------------------------------------------------------------
// Flash attention (causal). Grid: (SEQ/128, B*H). 8 waves, 16 q-rows each.
// Double-buffered K/V with stage-ahead + counted vmcnt(4); P-scratch bf16.
// LDS 80KB -> 2 blocks/CU.
// Q [B,S,H*dk], K [B,S,H*dk], V^T [B,H,dk,S], O [B,S,H*dk] (all bf16)
// ---------------------------------------------------------------------------
__global__ __launch_bounds__(512, 4) void attn_kernel(
    const __hip_bfloat16* __restrict__ Qm, const __hip_bfloat16* __restrict__ Km,
    const __hip_bfloat16* __restrict__ Vt, __hip_bfloat16* __restrict__ Om) {
  __shared__ __align__(16) unsigned char Kl[2][16384];  // [64 t][128 d] swizzled
  __shared__ __align__(16) unsigned char Vl[2][16384];  // [128 d][64 t] swizzled
  __shared__ __align__(16) unsigned char Pl[16384];     // per-wave 2KB bf16 [16 q][64 t]
  const int tid = threadIdx.x;
  const int lane = tid & 63, w = tid >> 6;  // w in 0..7
  const int l15 = lane & 15, lg = lane >> 4;
  const int bh = blockIdx.y, b = bh >> 4, h = bh & 15;
  const int q0 = blockIdx.x * 128;
  const int qw = q0 + w * 16;
  const int row8 = lane >> 3;
  const int nt = (q0 >> 6) + 2;  // K/V tiles 0 .. q0/64+1

  // Q fragments (A-operand): row = l15, k = ks*32 + lg*8 .. +8
  short8 qf[4];
  const __hip_bfloat16* qbase = Qm + (size_t)(b * SEQ + qw + l15) * D_MODEL + h * DK;
#pragma unroll
  for (int ks = 0; ks < 4; ++ks) qf[ks] = *(const short8*)(qbase + ks * 32 + lg * 8);

  float m_run[4], l_run[4];
  f32x4 acc_o[8];
#pragma unroll
  for (int r = 0; r < 4; ++r) { m_run[r] = -1e30f; l_run[r] = 0.0f; }
#pragma unroll
  for (int fd = 0; fd < 8; ++fd) acc_o[fd] = (f32x4){0.f, 0.f, 0.f, 0.f};

  auto STAGE = [&](int tt) {
    unsigned char* kb = Kl[tt & 1];
    unsigned char* vb = Vl[tt & 1];
    const int t0 = tt * 64;
#pragma unroll
    for (int i = 0; i < 2; ++i) {
      const int c = w * 2 + i;
      const int row = c * 4 + lg;
      const int gcb = l15 ^ (row & 7);
      GLOAD16(Km + (size_t)(b * SEQ + t0 + row) * D_MODEL + h * DK + gcb * 8,
              kb + c * 1024);
    }
#pragma unroll
    for (int i = 0; i < 2; ++i) {
      const int c = w * 2 + i;
      const int row = c * 8 + row8;
      const int gcb = (lane & 7) ^ (row & 7);
      GLOAD16(Vt + (size_t)(bh * DK + row) * SEQ + t0 + gcb * 8, vb + c * 1024);
    }
  };

  STAGE(0);
  for (int t = 0; t < nt; ++t) {
    const int t0 = t * 64;
    if (t + 1 < nt) {
      STAGE(t + 1);  // 4 loads -> in flight across this tile's compute
      asm volatile("s_waitcnt vmcnt(4)" ::: "memory");  // tile t complete
    } else {
      asm volatile("s_waitcnt vmcnt(0)" ::: "memory");
    }
    __builtin_amdgcn_s_barrier();  // all waves: tile t in LDS; t-1 reads done
    asm volatile("" ::: "memory");
    if (t0 <= qw + 15) {
      const unsigned char* kb = Kl[t & 1];
      const unsigned char* vb = Vl[t & 1];
      // S = Q K^T  (output: row q = lg*4+r, col key = l15 within frag fn)
      f32x4 sacc[4];
#pragma unroll
      for (int fn = 0; fn < 4; ++fn) sacc[fn] = (f32x4){0.f, 0.f, 0.f, 0.f};
#pragma unroll
      for (int ks = 0; ks < 4; ++ks) {
        const int cb = ks * 4 + lg;
#pragma unroll
        for (int fn = 0; fn < 4; ++fn) {
          const int rn = fn * 16 + l15;
          short8 kf = *(const short8*)(kb + rn * 256 + ((cb ^ (rn & 7)) << 4));
          sacc[fn] = MFMA16(qf[ks], kf, sacc[fn]);
        }
      }
      const float scale = 0.088388347648318447f;  // 1/sqrt(128)
      float mt[4] = {-1e30f, -1e30f, -1e30f, -1e30f};
#pragma unroll
      for (int fn = 0; fn < 4; ++fn) {
        const int key = t0 + fn * 16 + l15;
#pragma unroll
        for (int r = 0; r < 4; ++r) {
          const int qg = qw + lg * 4 + r;
          float sv = sacc[fn][r] * scale;
          sv = (key <= qg) ? sv : -1e30f;
          sacc[fn][r] = sv;
          mt[r] = fmaxf(mt[r], sv);
        }
      }
      float alpha[4], ls[4];
#pragma unroll
      for (int r = 0; r < 4; ++r) {
#pragma unroll
        for (int off = 1; off < 16; off <<= 1) mt[r] = fmaxf(mt[r], __shfl_xor(mt[r], off));
        const float mnew = fmaxf(m_run[r], mt[r]);
        alpha[r] = __expf(m_run[r] - mnew);
        m_run[r] = mnew;
        ls[r] = 0.0f;
      }
#pragma unroll
      for (int fn = 0; fn < 4; ++fn)
#pragma unroll
        for (int r = 0; r < 4; ++r) {
          const float p = __expf(sacc[fn][r] - m_run[r]);
          sacc[fn][r] = p;
          ls[r] += p;
        }
#pragma unroll
      for (int r = 0; r < 4; ++r) {
#pragma unroll
        for (int off = 1; off < 16; off <<= 1) ls[r] += __shfl_xor(ls[r], off);
        l_run[r] = l_run[r] * alpha[r] + ls[r];
      }
#pragma unroll
      for (int fd = 0; fd < 8; ++fd)
#pragma unroll
        for (int r = 0; r < 4; ++r) acc_o[fd][r] *= alpha[r];
      // write P (bf16) to wave-local LDS: row q (128B), 16B slot = (t>>3)^(q&7)
      unsigned char* pw = Pl + w * 2048;
#pragma unroll
      for (int fn = 0; fn < 4; ++fn) {
        const int tt = fn * 16 + l15;
#pragma unroll
        for (int r = 0; r < 4; ++r) {
          const int qq = lg * 4 + r;
          *(unsigned short*)(pw + qq * 128 + (((tt >> 3) ^ (qq & 7)) << 4) +
                             (tt & 7) * 2) = f2bf(sacc[fn][r]);
        }
      }
      // O += P V  (A-operand P: row q = l15, k-slot tb = ks*4+lg)
#pragma unroll
      for (int ks = 0; ks < 2; ++ks) {
        const int tb = ks * 4 + lg;
        short8 pf = *(const short8*)(Pl + w * 2048 + l15 * 128 +
                                     ((tb ^ (l15 & 7)) << 4));
        const int cb = ks * 4 + lg;
#pragma unroll
        for (int fd = 0; fd < 8; ++fd) {
          const int rv = fd * 16 + l15;
          short8 vf = *(const short8*)(vb + rv * 128 + ((cb ^ (rv & 7)) << 4));
          acc_o[fd] = MFMA16(pf, vf, acc_o[fd]);
        }
      }
    }
    asm volatile("" ::: "memory");
    __builtin_amdgcn_s_barrier();  // all reads of buf[t&1] done before t+2 stages it
    asm volatile("" ::: "memory");
  }
#pragma unroll
  for (int r = 0; r < 4; ++r) {
    const float inv = 1.0f / l_run[r];
    const int qg = qw + lg * 4 + r;
    __hip_bfloat16* ob = Om + (size_t)(b * SEQ + qg) * D_MODEL + h * DK + l15;
#pragma unroll
    for (int fd = 0; fd < 8; ++fd)
      ob[fd * 16] = __float2bfloat16(acc_o[fd][r] * inv);
  }
}

// ---------------------------------------------------------------------------
// Workspace layout (192 MiB peak, time-shared):
//   @0   Hb   (32M)  LN1 out -> later LN2 out
//   @32  Q    (32M)  -> after attn: W1T (32M)
//   @64  K    (32M)  -> after attn: W2T (32M)
//   @96  Vt   (32M)  -\
//   @128 AO   (32M)  --> after O-proj: FF1 chunk (64M, 4096x8192 bf16)
//   @160 WqT(8) WkT(8) WvT(8) WoT(8)
// X2 (f32 residual stream) lives in d_out itself.
// ---------------------------------------------------------------------------
extern "C" void kernel_launch(void* const* d_in, const int* in_sizes, int n_in,
                              void* d_out, int out_size, void* d_ws, size_t ws_size,
                              hipStream_t stream) {
  (void)in_sizes; (void)n_in; (void)out_size;
  const size_t MB = 1024 * 1024;
  if (ws_size < 192 * MB) return;  // diagnostic guard: clean absmax-fail, not a fault

  const float* x  = (const float*)d_in[0];
  const float* Wq = (const float*)d_in[1];
  const float* bq = (const float*)d_in[2];
  const float* Wk = (const float*)d_in[3];
  const float* bk = (const float*)d_in[4];
  const float* Wv = (const float*)d_in[5];
  const float* bv = (const float*)d_in[6];
  const float* Wo = (const float*)d_in[7];
  const float* bo = (const float*)d_in[8];
  const float* W1 = (const float*)d_in[9];
  const float* b1 = (const float*)d_in[10];
  const float* W2 = (const float*)d_in[11];
  const float* b2 = (const float*)d_in[12];
  const float* g1 = (const float*)d_in[13];
  const float* be1 = (const float*)d_in[14];
  const float* g2 = (const float*)d_in[15];
  const float* be2 = (const float*)d_in[16];

  char* ws = (char*)d_ws;
  __hip_bfloat16* Hb  = (__hip_bfloat16*)(ws + 0 * MB);
  __hip_bfloat16* Qb  = (__hip_bfloat16*)(ws + 32 * MB);
  __hip_bfloat16* Kb  = (__hip_bfloat16*)(ws + 64 * MB);
  __hip_bfloat16* Vtb = (__hip_bfloat16*)(ws + 96 * MB);
  __hip_bfloat16* AOb = (__hip_bfloat16*)(ws + 128 * MB);
  __hip_bfloat16* W1T = (__hip_bfloat16*)(ws + 32 * MB);   // after attn
  __hip_bfloat16* W2T = (__hip_bfloat16*)(ws + 64 * MB);   // after attn
  __hip_bfloat16* FF1 = (__hip_bfloat16*)(ws + 96 * MB);   // after O-proj
  __hip_bfloat16* WqT = (__hip_bfloat16*)(ws + 160 * MB);
  __hip_bfloat16* WkT = (__hip_bfloat16*)(ws + 168 * MB);
  __hip_bfloat16* WvT = (__hip_bfloat16*)(ws + 176 * MB);
  __hip_bfloat16* WoT = (__hip_bfloat16*)(ws + 184 * MB);
  float* X2 = (float*)d_out;  // residual stream lives in d_out

  const dim3 tb(256);
  // small weight converts (f32 [K][N] -> bf16 [N][K])
  transpose_cvt_kernel<<<dim3(64, 64), tb, 0, stream>>>(Wq, WqT, 2048, 2048);
  transpose_cvt_kernel<<<dim3(64, 64), tb, 0, stream>>>(Wk, WkT, 2048, 2048);
  transpose_cvt_kernel<<<dim3(64, 64), tb, 0, stream>>>(Wv, WvT, 2048, 2048);
  transpose_cvt_kernel<<<dim3(64, 64), tb, 0, stream>>>(Wo, WoT, 2048, 2048);

  layernorm_kernel<<<MTOT, tb, 0, stream>>>(x, g1, be1, Hb);

  // QKV: M=8192 -> 32 row-tiles of 256; N=2048 -> 16 col-tiles of 128
  const dim3 gQKV(2048 / 128, MTOT / 256);
  gemm_kernel<EPI_BF16><<<gQKV, 512, 0, stream>>>(Hb, WqT, bq, nullptr, Qb, MTOT, 2048, 2048);
  gemm_kernel<EPI_BF16><<<gQKV, 512, 0, stream>>>(Hb, WkT, bk, nullptr, Kb, MTOT, 2048, 2048);
  gemm_kernel<EPI_VT><<<gQKV, 512, 0, stream>>>(Hb, WvT, bv, nullptr, Vtb, MTOT, 2048, 2048);

  attn_kernel<<<dim3(SEQ / 128, BATCH * NUM_HEADS), dim3(512), 0, stream>>>(Qb, Kb, Vtb, AOb);

  // Q/K regions now dead -> convert FFN weights into them
  transpose_cvt_kernel<<<dim3(256, 64), tb, 0, stream>>>(W1, W1T, 2048, 8192);
  transpose_cvt_kernel<<<dim3(64, 256), tb, 0, stream>>>(W2, W2T, 8192, 2048);

  // O-proj + residual -> X2 (= d_out, f32)
  gemm_kernel<EPI_RESID><<<gQKV, 512, 0, stream>>>(AOb, WoT, bo, x, X2, MTOT, 2048, 2048);

  layernorm_kernel<<<MTOT, tb, 0, stream>>>(X2, g2, be2, Hb);

  // FFN in 2 chunks of 4096 rows (FF1 chunk reuses Vt+AO regions, 64 MiB)
  for (int c = 0; c < 2; ++c) {
    const size_t moff = (size_t)c * 4096;
    gemm_kernel<EPI_GELU><<<dim3(8192 / 128, 4096 / 256), 512, 0, stream>>>(
        Hb + moff * D_MODEL, W1T, b1, nullptr, FF1, 4096, 8192, 2048);
    gemm_kernel<EPI_RESID><<<dim3(2048 / 128, 4096 / 256), 512, 0, stream>>>(
        FF1, W2T, b2, X2 + moff * D_MODEL, X2 + moff * D_MODEL, 4096, 2048, 8192);
  }
}

// Round 8
// 1328.219 us; speedup vs baseline: 1.1445x; 1.0150x over previous
//
#include <hip/hip_runtime.h>
#include <hip/hip_bf16.h>

#define D_MODEL 2048
#define NUM_HEADS 16
#define D_FF 8192
#define BATCH 4
#define SEQ 2048
#define DK 128
#define MTOT (BATCH * SEQ)  // 8192

typedef __attribute__((ext_vector_type(8))) short short8;
typedef __attribute__((ext_vector_type(4))) short short4v;
typedef __attribute__((ext_vector_type(4))) float f32x4;

#define MFMA16(a, b, c) __builtin_amdgcn_mfma_f32_16x16x32_bf16(a, b, c, 0, 0, 0)

#define GLOAD16(gp, lp)                                                        \
  __builtin_amdgcn_global_load_lds(                                            \
      (const __attribute__((address_space(1))) void*)(gp),                     \
      (__attribute__((address_space(3))) void*)(lp), 16, 0, 0)

static __device__ __forceinline__ unsigned short f2bf(float f) {
  return __builtin_bit_cast(unsigned short, __float2bfloat16(f));
}

// ---------------------------------------------------------------------------
// Weight convert + transpose: in f32 [K][N] -> out bf16 [N][K]
// ---------------------------------------------------------------------------
__global__ __launch_bounds__(256) void transpose_cvt_kernel(
    const float* __restrict__ in, __hip_bfloat16* __restrict__ out, int K, int N) {
  __shared__ float tile[32][33];
  const int n0 = blockIdx.x * 32, k0 = blockIdx.y * 32;
  const int tx = threadIdx.x & 31, ty = threadIdx.x >> 5;  // 32 x 8
#pragma unroll
  for (int i = 0; i < 4; ++i)
    tile[ty + i * 8][tx] = in[(size_t)(k0 + ty + i * 8) * N + n0 + tx];
  __syncthreads();
#pragma unroll
  for (int i = 0; i < 4; ++i)
    out[(size_t)(n0 + ty + i * 8) * K + k0 + tx] = __float2bfloat16(tile[tx][ty + i * 8]);
}

// ---------------------------------------------------------------------------
// LayerNorm: f32 [M][D_MODEL] -> bf16 [M][D_MODEL]
// ---------------------------------------------------------------------------
__global__ __launch_bounds__(256) void layernorm_kernel(
    const float* __restrict__ x, const float* __restrict__ g,
    const float* __restrict__ bta, __hip_bfloat16* __restrict__ out) {
  const int row = blockIdx.x;
  const int tid = threadIdx.x;
  const float* xr = x + (size_t)row * D_MODEL;
  float4 v0 = *(const float4*)(xr + tid * 8);
  float4 v1 = *(const float4*)(xr + tid * 8 + 4);
  float s = v0.x + v0.y + v0.z + v0.w + v1.x + v1.y + v1.z + v1.w;
  float q = v0.x * v0.x + v0.y * v0.y + v0.z * v0.z + v0.w * v0.w +
            v1.x * v1.x + v1.y * v1.y + v1.z * v1.z + v1.w * v1.w;
#pragma unroll
  for (int off = 1; off < 64; off <<= 1) {
    s += __shfl_xor(s, off);
    q += __shfl_xor(q, off);
  }
  __shared__ float rs[4], rq[4];
  if ((tid & 63) == 0) {
    rs[tid >> 6] = s;
    rq[tid >> 6] = q;
  }
  __syncthreads();
  s = rs[0] + rs[1] + rs[2] + rs[3];
  q = rq[0] + rq[1] + rq[2] + rq[3];
  const float mu = s * (1.0f / D_MODEL);
  const float var = q * (1.0f / D_MODEL) - mu * mu;
  const float rstd = rsqrtf(var + 1e-5f);
  float4 g0 = *(const float4*)(g + tid * 8);
  float4 g1 = *(const float4*)(g + tid * 8 + 4);
  float4 b0 = *(const float4*)(bta + tid * 8);
  float4 b1 = *(const float4*)(bta + tid * 8 + 4);
  short8 o;
  o[0] = (short)f2bf((v0.x - mu) * rstd * g0.x + b0.x);
  o[1] = (short)f2bf((v0.y - mu) * rstd * g0.y + b0.y);
  o[2] = (short)f2bf((v0.z - mu) * rstd * g0.z + b0.z);
  o[3] = (short)f2bf((v0.w - mu) * rstd * g0.w + b0.w);
  o[4] = (short)f2bf((v1.x - mu) * rstd * g1.x + b1.x);
  o[5] = (short)f2bf((v1.y - mu) * rstd * g1.y + b1.y);
  o[6] = (short)f2bf((v1.z - mu) * rstd * g1.z + b1.z);
  o[7] = (short)f2bf((v1.w - mu) * rstd * g1.w + b1.w);
  *(short8*)(out + (size_t)row * D_MODEL + tid * 8) = o;
}

// ---------------------------------------------------------------------------
// GEMM: C[M][N] = A[M][K] @ Bt[N][K]^T (+bias, epilogue variants)
// 256x128 tile, BK=64, 8 waves (4Mx2N), 3-buffer LDS ring (144 KiB).
// Counted-vmcnt pipeline: one s_barrier per K-tile, 2 tiles (12 loads)
// always in flight, vmcnt never drained in the main loop.  (round-7 version)
// ---------------------------------------------------------------------------
enum { EPI_BF16 = 0, EPI_VT = 1, EPI_RESID = 2, EPI_GELU = 3 };

template <int EPI>
__global__ __launch_bounds__(512, 2) void gemm_kernel(
    const __hip_bfloat16* __restrict__ A, const __hip_bfloat16* __restrict__ Bt,
    const float* __restrict__ bias, const float* __restrict__ resid,
    void* __restrict__ outv, int M, int N, int K) {
  __shared__ __align__(16) unsigned char lds[3][49152];  // [ring][A 32K | B 16K]
  const int tid = threadIdx.x;
  const int lane = tid & 63, w = tid >> 6;  // 8 waves
  const int l15 = lane & 15, lg = lane >> 4;
  const int m0 = blockIdx.y * 256, n0 = blockIdx.x * 128;
  const int wm = (w >> 1) * 64, wn = (w & 1) * 64;

  f32x4 acc[4][4] = {};

  const int row8 = lane >> 3;        // 0..7 (row within 8-row chunk)
  const int g8 = (lane & 7) ^ row8;  // pre-swizzled source 16B-block

  auto STAGE = [&](int tt) {
    unsigned char* db = lds[tt % 3];
    const size_t ko = (size_t)tt * 64;
#pragma unroll
    for (int i = 0; i < 4; ++i) {
      const int c = w * 4 + i;  // A chunk 0..31 (8 rows x 128B each)
      const int row = c * 8 + row8;
      GLOAD16(A + (size_t)(m0 + row) * K + ko + g8 * 8, db + c * 1024);
    }
#pragma unroll
    for (int i = 0; i < 2; ++i) {
      const int c = w * 2 + i;  // B chunk 0..15
      const int row = c * 8 + row8;
      GLOAD16(Bt + (size_t)(n0 + row) * K + ko + g8 * 8, db + 32768 + c * 1024);
    }
  };
  auto COMPUTE = [&](int tt) {
    const unsigned char* db = lds[tt % 3];
#pragma unroll
    for (int ks = 0; ks < 2; ++ks) {
      const int cb = ks * 4 + lg;
      short8 af[4], bf[4];
#pragma unroll
      for (int f = 0; f < 4; ++f) {
        const int ra = wm + f * 16 + l15;
        af[f] = *(const short8*)(db + ra * 128 + ((cb ^ (ra & 7)) << 4));
        const int rb = wn + f * 16 + l15;
        bf[f] = *(const short8*)(db + 32768 + rb * 128 + ((cb ^ (rb & 7)) << 4));
      }
      __builtin_amdgcn_s_setprio(1);
#pragma unroll
      for (int fi = 0; fi < 4; ++fi)
#pragma unroll
        for (int fj = 0; fj < 4; ++fj)
          acc[fi][fj] = MFMA16(af[fi], bf[fj], acc[fi][fj]);
      __builtin_amdgcn_s_setprio(0);
    }
  };

  const int nt = K >> 6;  // K-tiles of 64
  STAGE(0);
  STAGE(1);
  for (int t = 0; t < nt; ++t) {
    if (t + 2 < nt) {
      asm volatile("s_waitcnt vmcnt(6)" ::: "memory");  // tile t complete
      __builtin_amdgcn_s_barrier();
      STAGE(t + 2);  // into buffer of tile t-1 (reads drained pre-barrier)
    } else if (t + 2 == nt) {
      asm volatile("s_waitcnt vmcnt(6)" ::: "memory");
      __builtin_amdgcn_s_barrier();
    } else {
      asm volatile("s_waitcnt vmcnt(0)" ::: "memory");
      __builtin_amdgcn_s_barrier();
    }
    COMPUTE(t);
  }

#pragma unroll
  for (int fi = 0; fi < 4; ++fi) {
#pragma unroll
    for (int fj = 0; fj < 4; ++fj) {
      const int mb = m0 + wm + fi * 16 + lg * 4;
      const int n = n0 + wn + fj * 16 + l15;
      const float bv = bias ? bias[n] : 0.0f;
      if constexpr (EPI == EPI_VT) {
        // out bf16 [B][H][DK][SEQ]; m -> (b, s), n -> (h, d)
        const int bb = mb >> 11, ss = mb & (SEQ - 1);
        const int hh = n >> 7, dd = n & (DK - 1);
        short4v pk;
#pragma unroll
        for (int r = 0; r < 4; ++r) pk[r] = (short)f2bf(acc[fi][fj][r] + bv);
        __hip_bfloat16* o = (__hip_bfloat16*)outv;
        *(short4v*)(o + ((size_t)((bb * NUM_HEADS + hh) * DK + dd)) * SEQ + ss) = pk;
      } else {
#pragma unroll
        for (int r = 0; r < 4; ++r) {
          const int m = mb + r;
          const float v = acc[fi][fj][r] + bv;
          if constexpr (EPI == EPI_BF16) {
            ((__hip_bfloat16*)outv)[(size_t)m * N + n] = __float2bfloat16(v);
          } else if constexpr (EPI == EPI_GELU) {
            const float ge = 0.5f * v * (1.0f + erff(v * 0.70710678118654752f));
            ((__hip_bfloat16*)outv)[(size_t)m * N + n] = __float2bfloat16(ge);
          } else {  // EPI_RESID (resid may alias outv: same-element read->write)
            ((float*)outv)[(size_t)m * N + n] = resid[(size_t)m * N + n] + v;
          }
        }
      }
    }
  }
}

// ---------------------------------------------------------------------------
// Flash attention (causal). Grid: (SEQ/128, B*H). 8 waves, 16 q-rows each.
// LPT dispatch: q0 = (gx-1-bx)*128 so longest blocks launch first (causal
// work imbalance 2..32 tiles; shortest-first was worst-case list scheduling).
// Double-buffered K/V, stage-ahead + counted vmcnt(4); bf16 P-scratch;
// defer-max (THR=8) skips rescale in the common case; setprio around MFMA.
// LDS 80KB -> 2 blocks/CU.
// ---------------------------------------------------------------------------
__global__ __launch_bounds__(512, 4) void attn_kernel(
    const __hip_bfloat16* __restrict__ Qm, const __hip_bfloat16* __restrict__ Km,
    const __hip_bfloat16* __restrict__ Vt, __hip_bfloat16* __restrict__ Om) {
  __shared__ __align__(16) unsigned char Kl[2][16384];  // [64 t][128 d] swizzled
  __shared__ __align__(16) unsigned char Vl[2][16384];  // [128 d][64 t] swizzled
  __shared__ __align__(16) unsigned char Pl[16384];     // per-wave 2KB bf16 [16 q][64 t]
  const int tid = threadIdx.x;
  const int lane = tid & 63, w = tid >> 6;  // w in 0..7
  const int l15 = lane & 15, lg = lane >> 4;
  const int bh = blockIdx.y, b = bh >> 4, h = bh & 15;
  const int q0 = ((int)gridDim.x - 1 - (int)blockIdx.x) * 128;  // LPT order
  const int qw = q0 + w * 16;
  const int row8 = lane >> 3;
  const int nt = (q0 >> 6) + 2;  // K/V tiles 0 .. q0/64+1

  // Q fragments (A-operand): row = l15, k = ks*32 + lg*8 .. +8
  short8 qf[4];
  const __hip_bfloat16* qbase = Qm + (size_t)(b * SEQ + qw + l15) * D_MODEL + h * DK;
#pragma unroll
  for (int ks = 0; ks < 4; ++ks) qf[ks] = *(const short8*)(qbase + ks * 32 + lg * 8);

  float m_run[4], l_run[4];
  f32x4 acc_o[8];
#pragma unroll
  for (int r = 0; r < 4; ++r) { m_run[r] = -1e30f; l_run[r] = 0.0f; }
#pragma unroll
  for (int fd = 0; fd < 8; ++fd) acc_o[fd] = (f32x4){0.f, 0.f, 0.f, 0.f};

  auto STAGE = [&](int tt) {
    unsigned char* kb = Kl[tt & 1];
    unsigned char* vb = Vl[tt & 1];
    const int t0 = tt * 64;
#pragma unroll
    for (int i = 0; i < 2; ++i) {
      const int c = w * 2 + i;
      const int row = c * 4 + lg;
      const int gcb = l15 ^ (row & 7);
      GLOAD16(Km + (size_t)(b * SEQ + t0 + row) * D_MODEL + h * DK + gcb * 8,
              kb + c * 1024);
    }
#pragma unroll
    for (int i = 0; i < 2; ++i) {
      const int c = w * 2 + i;
      const int row = c * 8 + row8;
      const int gcb = (lane & 7) ^ (row & 7);
      GLOAD16(Vt + (size_t)(bh * DK + row) * SEQ + t0 + gcb * 8, vb + c * 1024);
    }
  };

  STAGE(0);
  for (int t = 0; t < nt; ++t) {
    const int t0 = t * 64;
    if (t + 1 < nt) {
      STAGE(t + 1);  // 4 loads -> in flight across this tile's compute
      asm volatile("s_waitcnt vmcnt(4)" ::: "memory");  // tile t complete
    } else {
      asm volatile("s_waitcnt vmcnt(0)" ::: "memory");
    }
    __builtin_amdgcn_s_barrier();  // all waves: tile t in LDS; t-1 reads done
    asm volatile("" ::: "memory");
    if (t0 <= qw + 15) {
      const unsigned char* kb = Kl[t & 1];
      const unsigned char* vb = Vl[t & 1];
      // S = Q K^T  (output: row q = lg*4+r, col key = l15 within frag fn)
      f32x4 sacc[4];
#pragma unroll
      for (int fn = 0; fn < 4; ++fn) sacc[fn] = (f32x4){0.f, 0.f, 0.f, 0.f};
      __builtin_amdgcn_s_setprio(1);
#pragma unroll
      for (int ks = 0; ks < 4; ++ks) {
        const int cb = ks * 4 + lg;
#pragma unroll
        for (int fn = 0; fn < 4; ++fn) {
          const int rn = fn * 16 + l15;
          short8 kf = *(const short8*)(kb + rn * 256 + ((cb ^ (rn & 7)) << 4));
          sacc[fn] = MFMA16(qf[ks], kf, sacc[fn]);
        }
      }
      __builtin_amdgcn_s_setprio(0);
      const float scale = 0.088388347648318447f;  // 1/sqrt(128)
      float mt[4] = {-1e30f, -1e30f, -1e30f, -1e30f};
#pragma unroll
      for (int fn = 0; fn < 4; ++fn) {
        const int key = t0 + fn * 16 + l15;
#pragma unroll
        for (int r = 0; r < 4; ++r) {
          const int qg = qw + lg * 4 + r;
          float sv = sacc[fn][r] * scale;
          sv = (key <= qg) ? sv : -1e30f;
          sacc[fn][r] = sv;
          mt[r] = fmaxf(mt[r], sv);
        }
      }
#pragma unroll
      for (int r = 0; r < 4; ++r)
#pragma unroll
        for (int off = 1; off < 16; off <<= 1) mt[r] = fmaxf(mt[r], __shfl_xor(mt[r], off));
      // defer-max (T13): skip rescale when tile max is within THR of running max
      int ok = 1;
#pragma unroll
      for (int r = 0; r < 4; ++r) ok = ok && (mt[r] <= m_run[r] + 8.0f);
      const bool defer = __all(ok);
      float alpha[4];
      if (!defer) {
#pragma unroll
        for (int r = 0; r < 4; ++r) {
          const float mnew = fmaxf(m_run[r], mt[r]);
          alpha[r] = __expf(m_run[r] - mnew);
          m_run[r] = mnew;
        }
      }
      float ls[4] = {0.f, 0.f, 0.f, 0.f};
#pragma unroll
      for (int fn = 0; fn < 4; ++fn)
#pragma unroll
        for (int r = 0; r < 4; ++r) {
          const float p = __expf(sacc[fn][r] - m_run[r]);
          sacc[fn][r] = p;
          ls[r] += p;
        }
#pragma unroll
      for (int r = 0; r < 4; ++r) {
#pragma unroll
        for (int off = 1; off < 16; off <<= 1) ls[r] += __shfl_xor(ls[r], off);
        l_run[r] = (defer ? l_run[r] : l_run[r] * alpha[r]) + ls[r];
      }
      if (!defer) {
#pragma unroll
        for (int fd = 0; fd < 8; ++fd)
#pragma unroll
          for (int r = 0; r < 4; ++r) acc_o[fd][r] *= alpha[r];
      }
      // write P (bf16) to wave-local LDS: row q (128B), 16B slot = (t>>3)^(q&7)
      unsigned char* pw = Pl + w * 2048;
#pragma unroll
      for (int fn = 0; fn < 4; ++fn) {
        const int tt = fn * 16 + l15;
#pragma unroll
        for (int r = 0; r < 4; ++r) {
          const int qq = lg * 4 + r;
          *(unsigned short*)(pw + qq * 128 + (((tt >> 3) ^ (qq & 7)) << 4) +
                             (tt & 7) * 2) = f2bf(sacc[fn][r]);
        }
      }
      // O += P V  (A-operand P: row q = l15, k-slot tb = ks*4+lg)
#pragma unroll
      for (int ks = 0; ks < 2; ++ks) {
        const int tb = ks * 4 + lg;
        short8 pf = *(const short8*)(Pl + w * 2048 + l15 * 128 +
                                     ((tb ^ (l15 & 7)) << 4));
        const int cb = ks * 4 + lg;
        __builtin_amdgcn_s_setprio(1);
#pragma unroll
        for (int fd = 0; fd < 8; ++fd) {
          const int rv = fd * 16 + l15;
          short8 vf = *(const short8*)(vb + rv * 128 + ((cb ^ (rv & 7)) << 4));
          acc_o[fd] = MFMA16(pf, vf, acc_o[fd]);
        }
        __builtin_amdgcn_s_setprio(0);
      }
    }
    asm volatile("" ::: "memory");
    __builtin_amdgcn_s_barrier();  // all reads of buf[t&1] done before t+2 stages it
    asm volatile("" ::: "memory");
  }
#pragma unroll
  for (int r = 0; r < 4; ++r) {
    const float inv = 1.0f / l_run[r];
    const int qg = qw + lg * 4 + r;
    __hip_bfloat16* ob = Om + (size_t)(b * SEQ + qg) * D_MODEL + h * DK + l15;
#pragma unroll
    for (int fd = 0; fd < 8; ++fd)
      ob[fd * 16] = __float2bfloat16(acc_o[fd][r] * inv);
  }
}

// ---------------------------------------------------------------------------
// Workspace layout (192 MiB peak, time-shared):
//   @0   Hb   (32M)  LN1 out -> later LN2 out
//   @32  Q    (32M)  -> after attn: W1T (32M)
//   @64  K    (32M)  -> after attn: W2T (32M)
//   @96  Vt   (32M)  -\
//   @128 AO   (32M)  --> after O-proj: FF1 chunk (64M, 4096x8192 bf16)
//   @160 WqT(8) WkT(8) WvT(8) WoT(8)
// X2 (f32 residual stream) lives in d_out itself.
// ---------------------------------------------------------------------------
extern "C" void kernel_launch(void* const* d_in, const int* in_sizes, int n_in,
                              void* d_out, int out_size, void* d_ws, size_t ws_size,
                              hipStream_t stream) {
  (void)in_sizes; (void)n_in; (void)out_size;
  const size_t MB = 1024 * 1024;
  if (ws_size < 192 * MB) return;  // diagnostic guard: clean absmax-fail, not a fault

  const float* x  = (const float*)d_in[0];
  const float* Wq = (const float*)d_in[1];
  const float* bq = (const float*)d_in[2];
  const float* Wk = (const float*)d_in[3];
  const float* bk = (const float*)d_in[4];
  const float* Wv = (const float*)d_in[5];
  const float* bv = (const float*)d_in[6];
  const float* Wo = (const float*)d_in[7];
  const float* bo = (const float*)d_in[8];
  const float* W1 = (const float*)d_in[9];
  const float* b1 = (const float*)d_in[10];
  const float* W2 = (const float*)d_in[11];
  const float* b2 = (const float*)d_in[12];
  const float* g1 = (const float*)d_in[13];
  const float* be1 = (const float*)d_in[14];
  const float* g2 = (const float*)d_in[15];
  const float* be2 = (const float*)d_in[16];

  char* ws = (char*)d_ws;
  __hip_bfloat16* Hb  = (__hip_bfloat16*)(ws + 0 * MB);
  __hip_bfloat16* Qb  = (__hip_bfloat16*)(ws + 32 * MB);
  __hip_bfloat16* Kb  = (__hip_bfloat16*)(ws + 64 * MB);
  __hip_bfloat16* Vtb = (__hip_bfloat16*)(ws + 96 * MB);
  __hip_bfloat16* AOb = (__hip_bfloat16*)(ws + 128 * MB);
  __hip_bfloat16* W1T = (__hip_bfloat16*)(ws + 32 * MB);   // after attn
  __hip_bfloat16* W2T = (__hip_bfloat16*)(ws + 64 * MB);   // after attn
  __hip_bfloat16* FF1 = (__hip_bfloat16*)(ws + 96 * MB);   // after O-proj
  __hip_bfloat16* WqT = (__hip_bfloat16*)(ws + 160 * MB);
  __hip_bfloat16* WkT = (__hip_bfloat16*)(ws + 168 * MB);
  __hip_bfloat16* WvT = (__hip_bfloat16*)(ws + 176 * MB);
  __hip_bfloat16* WoT = (__hip_bfloat16*)(ws + 184 * MB);
  float* X2 = (float*)d_out;  // residual stream lives in d_out

  const dim3 tb(256);
  // small weight converts (f32 [K][N] -> bf16 [N][K])
  transpose_cvt_kernel<<<dim3(64, 64), tb, 0, stream>>>(Wq, WqT, 2048, 2048);
  transpose_cvt_kernel<<<dim3(64, 64), tb, 0, stream>>>(Wk, WkT, 2048, 2048);
  transpose_cvt_kernel<<<dim3(64, 64), tb, 0, stream>>>(Wv, WvT, 2048, 2048);
  transpose_cvt_kernel<<<dim3(64, 64), tb, 0, stream>>>(Wo, WoT, 2048, 2048);

  layernorm_kernel<<<MTOT, tb, 0, stream>>>(x, g1, be1, Hb);

  // QKV: M=8192 -> 32 row-tiles of 256; N=2048 -> 16 col-tiles of 128
  const dim3 gQKV(2048 / 128, MTOT / 256);
  gemm_kernel<EPI_BF16><<<gQKV, 512, 0, stream>>>(Hb, WqT, bq, nullptr, Qb, MTOT, 2048, 2048);
  gemm_kernel<EPI_BF16><<<gQKV, 512, 0, stream>>>(Hb, WkT, bk, nullptr, Kb, MTOT, 2048, 2048);
  gemm_kernel<EPI_VT><<<gQKV, 512, 0, stream>>>(Hb, WvT, bv, nullptr, Vtb, MTOT, 2048, 2048);

  attn_kernel<<<dim3(SEQ / 128, BATCH * NUM_HEADS), dim3(512), 0, stream>>>(Qb, Kb, Vtb, AOb);

  // Q/K regions now dead -> convert FFN weights into them
  transpose_cvt_kernel<<<dim3(256, 64), tb, 0, stream>>>(W1, W1T, 2048, 8192);
  transpose_cvt_kernel<<<dim3(64, 256), tb, 0, stream>>>(W2, W2T, 8192, 2048);

  // O-proj + residual -> X2 (= d_out, f32)
  gemm_kernel<EPI_RESID><<<gQKV, 512, 0, stream>>>(AOb, WoT, bo, x, X2, MTOT, 2048, 2048);

  layernorm_kernel<<<MTOT, tb, 0, stream>>>(X2, g2, be2, Hb);

  // FFN in 2 chunks of 4096 rows (FF1 chunk reuses Vt+AO regions, 64 MiB)
  for (int c = 0; c < 2; ++c) {
    const size_t moff = (size_t)c * 4096;
    gemm_kernel<EPI_GELU><<<dim3(8192 / 128, 4096 / 256), 512, 0, stream>>>(
        Hb + moff * D_MODEL, W1T, b1, nullptr, FF1, 4096, 8192, 2048);
    gemm_kernel<EPI_RESID><<<dim3(2048 / 128, 4096 / 256), 512, 0, stream>>>(
        FF1, W2T, b2, X2 + moff * D_MODEL, X2 + moff * D_MODEL, 4096, 2048, 8192);
  }
}

// Round 9
// 1274.453 us; speedup vs baseline: 1.1927x; 1.0422x over previous
//
#include <hip/hip_runtime.h>
#include <hip/hip_bf16.h>

#define D_MODEL 2048
#define NUM_HEADS 16
#define D_FF 8192
#define BATCH 4
#define SEQ 2048
#define DK 128
#define MTOT (BATCH * SEQ)  // 8192

typedef __attribute__((ext_vector_type(8))) short short8;
typedef __attribute__((ext_vector_type(4))) short short4v;
typedef __attribute__((ext_vector_type(4))) float f32x4;

#define MFMA16(a, b, c) __builtin_amdgcn_mfma_f32_16x16x32_bf16(a, b, c, 0, 0, 0)

#define GLOAD16(gp, lp)                                                        \
  __builtin_amdgcn_global_load_lds(                                            \
      (const __attribute__((address_space(1))) void*)(gp),                     \
      (__attribute__((address_space(3))) void*)(lp), 16, 0, 0)

static __device__ __forceinline__ unsigned short f2bf(float f) {
  return __builtin_bit_cast(unsigned short, __float2bfloat16(f));
}

// ---------------------------------------------------------------------------
// Weight convert + transpose: in f32 [K][N] -> out bf16 [N][K]
// ---------------------------------------------------------------------------
__global__ __launch_bounds__(256) void transpose_cvt_kernel(
    const float* __restrict__ in, __hip_bfloat16* __restrict__ out, int K, int N) {
  __shared__ float tile[32][33];
  const int n0 = blockIdx.x * 32, k0 = blockIdx.y * 32;
  const int tx = threadIdx.x & 31, ty = threadIdx.x >> 5;  // 32 x 8
#pragma unroll
  for (int i = 0; i < 4; ++i)
    tile[ty + i * 8][tx] = in[(size_t)(k0 + ty + i * 8) * N + n0 + tx];
  __syncthreads();
#pragma unroll
  for (int i = 0; i < 4; ++i)
    out[(size_t)(n0 + ty + i * 8) * K + k0 + tx] = __float2bfloat16(tile[tx][ty + i * 8]);
}

// ---------------------------------------------------------------------------
// LayerNorm: f32 [M][D_MODEL] -> bf16 [M][D_MODEL]
// ---------------------------------------------------------------------------
__global__ __launch_bounds__(256) void layernorm_kernel(
    const float* __restrict__ x, const float* __restrict__ g,
    const float* __restrict__ bta, __hip_bfloat16* __restrict__ out) {
  const int row = blockIdx.x;
  const int tid = threadIdx.x;
  const float* xr = x + (size_t)row * D_MODEL;
  float4 v0 = *(const float4*)(xr + tid * 8);
  float4 v1 = *(const float4*)(xr + tid * 8 + 4);
  float s = v0.x + v0.y + v0.z + v0.w + v1.x + v1.y + v1.z + v1.w;
  float q = v0.x * v0.x + v0.y * v0.y + v0.z * v0.z + v0.w * v0.w +
            v1.x * v1.x + v1.y * v1.y + v1.z * v1.z + v1.w * v1.w;
#pragma unroll
  for (int off = 1; off < 64; off <<= 1) {
    s += __shfl_xor(s, off);
    q += __shfl_xor(q, off);
  }
  __shared__ float rs[4], rq[4];
  if ((tid & 63) == 0) {
    rs[tid >> 6] = s;
    rq[tid >> 6] = q;
  }
  __syncthreads();
  s = rs[0] + rs[1] + rs[2] + rs[3];
  q = rq[0] + rq[1] + rq[2] + rq[3];
  const float mu = s * (1.0f / D_MODEL);
  const float var = q * (1.0f / D_MODEL) - mu * mu;
  const float rstd = rsqrtf(var + 1e-5f);
  float4 g0 = *(const float4*)(g + tid * 8);
  float4 g1 = *(const float4*)(g + tid * 8 + 4);
  float4 b0 = *(const float4*)(bta + tid * 8);
  float4 b1 = *(const float4*)(bta + tid * 8 + 4);
  short8 o;
  o[0] = (short)f2bf((v0.x - mu) * rstd * g0.x + b0.x);
  o[1] = (short)f2bf((v0.y - mu) * rstd * g0.y + b0.y);
  o[2] = (short)f2bf((v0.z - mu) * rstd * g0.z + b0.z);
  o[3] = (short)f2bf((v0.w - mu) * rstd * g0.w + b0.w);
  o[4] = (short)f2bf((v1.x - mu) * rstd * g1.x + b1.x);
  o[5] = (short)f2bf((v1.y - mu) * rstd * g1.y + b1.y);
  o[6] = (short)f2bf((v1.z - mu) * rstd * g1.z + b1.z);
  o[7] = (short)f2bf((v1.w - mu) * rstd * g1.w + b1.w);
  *(short8*)(out + (size_t)row * D_MODEL + tid * 8) = o;
}

// ---------------------------------------------------------------------------
// GEMM v3: C[M][N] = A[M][K] @ Bt[N][K]^T (+bias, epilogue variants)
// 256x256 tile, BK=64, 8 waves (2Mx4N), double-buffered LDS (128 KiB).
// Per K-tile: counted vmcnt(8) (2 tiles in flight, never drained mid-loop),
// barrier, 64 MFMA/wave, barrier, STAGE(t+2). XCD-bijective block remap:
// d = (r&7) + 8*(c + nbx*(r>>3)) -> blocks sharing an A-panel on one XCD.
// LDS 128B rows, XOR-(row&7) 16B-block swizzle (pre-swizzled source).
// ---------------------------------------------------------------------------
enum { EPI_BF16 = 0, EPI_VT = 1, EPI_RESID = 2, EPI_GELU = 3 };

template <int EPI>
__global__ __launch_bounds__(512, 2) void gemm_kernel(
    const __hip_bfloat16* __restrict__ A, const __hip_bfloat16* __restrict__ Bt,
    const float* __restrict__ bias, const float* __restrict__ resid,
    void* __restrict__ outv, int M, int N, int K, int nbx) {
  __shared__ __align__(16) unsigned char lds[2][65536];  // [dbuf][A 32K | B 32K]
  const int tid = threadIdx.x;
  const int lane = tid & 63, w = tid >> 6;  // 8 waves
  const int l15 = lane & 15, lg = lane >> 4;
  // XCD-bijective decode: r&7 = d&7; q=d>>3; c=q%nbx; r=(q/nbx)*8+(d&7)
  const int d = blockIdx.x;
  const int qd = d >> 3;
  const int cC = qd % nbx;
  const int rC = (qd / nbx) * 8 + (d & 7);
  const int m0 = rC * 256, n0 = cC * 256;
  const int wm = (w >> 2) * 128, wn = (w & 3) * 64;

  f32x4 acc[8][4] = {};

  const int row8 = lane >> 3;        // 0..7 (row within 8-row chunk)
  const int g8 = (lane & 7) ^ row8;  // pre-swizzled source 16B-block

  auto STAGE = [&](int tt) {
    unsigned char* db = lds[tt & 1];
    const size_t ko = (size_t)tt * 64;
#pragma unroll
    for (int i = 0; i < 4; ++i) {
      const int c = w * 4 + i;  // A chunk 0..31 (8 rows x 128B each)
      const int row = c * 8 + row8;
      GLOAD16(A + (size_t)(m0 + row) * K + ko + g8 * 8, db + c * 1024);
    }
#pragma unroll
    for (int i = 0; i < 4; ++i) {
      const int c = w * 4 + i;  // B chunk 0..31
      const int row = c * 8 + row8;
      GLOAD16(Bt + (size_t)(n0 + row) * K + ko + g8 * 8, db + 32768 + c * 1024);
    }
  };
  auto COMPUTE = [&](int tt) {
    const unsigned char* db = lds[tt & 1];
#pragma unroll
    for (int ks = 0; ks < 2; ++ks) {
      const int cb = ks * 4 + lg;
      short8 af[8], bf[4];
#pragma unroll
      for (int f = 0; f < 8; ++f) {
        const int ra = wm + f * 16 + l15;
        af[f] = *(const short8*)(db + ra * 128 + ((cb ^ (ra & 7)) << 4));
      }
#pragma unroll
      for (int f = 0; f < 4; ++f) {
        const int rb = wn + f * 16 + l15;
        bf[f] = *(const short8*)(db + 32768 + rb * 128 + ((cb ^ (rb & 7)) << 4));
      }
      __builtin_amdgcn_s_setprio(1);
#pragma unroll
      for (int fi = 0; fi < 8; ++fi)
#pragma unroll
        for (int fj = 0; fj < 4; ++fj)
          acc[fi][fj] = MFMA16(af[fi], bf[fj], acc[fi][fj]);
      __builtin_amdgcn_s_setprio(0);
    }
  };

  const int nt = K >> 6;  // K-tiles of 64
  STAGE(0);
  STAGE(1);
  for (int t = 0; t < nt; ++t) {
    if (t < nt - 1)
      asm volatile("s_waitcnt vmcnt(8)" ::: "memory");  // tile t fully landed
    else
      asm volatile("s_waitcnt vmcnt(0)" ::: "memory");
    __builtin_amdgcn_s_barrier();  // all waves' tile-t loads in LDS
    COMPUTE(t);
    asm volatile("" ::: "memory");
    __builtin_amdgcn_s_barrier();  // all reads of buf t&1 done
    if (t + 2 < nt) STAGE(t + 2);  // overwrites buf t&1
  }

#pragma unroll
  for (int fi = 0; fi < 8; ++fi) {
#pragma unroll
    for (int fj = 0; fj < 4; ++fj) {
      const int mb = m0 + wm + fi * 16 + lg * 4;
      const int n = n0 + wn + fj * 16 + l15;
      const float bv = bias ? bias[n] : 0.0f;
      if constexpr (EPI == EPI_VT) {
        // out bf16 [B][H][DK][SEQ]; m -> (b, s), n -> (h, d)
        const int bb = mb >> 11, ss = mb & (SEQ - 1);
        const int hh = n >> 7, dd = n & (DK - 1);
        short4v pk;
#pragma unroll
        for (int r = 0; r < 4; ++r) pk[r] = (short)f2bf(acc[fi][fj][r] + bv);
        __hip_bfloat16* o = (__hip_bfloat16*)outv;
        *(short4v*)(o + ((size_t)((bb * NUM_HEADS + hh) * DK + dd)) * SEQ + ss) = pk;
      } else {
#pragma unroll
        for (int r = 0; r < 4; ++r) {
          const int m = mb + r;
          const float v = acc[fi][fj][r] + bv;
          if constexpr (EPI == EPI_BF16) {
            ((__hip_bfloat16*)outv)[(size_t)m * N + n] = __float2bfloat16(v);
          } else if constexpr (EPI == EPI_GELU) {
            const float ge = 0.5f * v * (1.0f + erff(v * 0.70710678118654752f));
            ((__hip_bfloat16*)outv)[(size_t)m * N + n] = __float2bfloat16(ge);
          } else {  // EPI_RESID (resid may alias outv: same-element read->write)
            ((float*)outv)[(size_t)m * N + n] = resid[(size_t)m * N + n] + v;
          }
        }
      }
    }
  }
}

// ---------------------------------------------------------------------------
// Flash attention (causal). Grid: (SEQ/128, B*H). 8 waves, 16 q-rows each.
// LPT dispatch; dbuf K/V stage-ahead + counted vmcnt(4); bf16 P-scratch with
// conflict-free slot = ((tt>>3)+qq+(qq>>3))&7; defer-max; setprio. 80KB LDS.
// ---------------------------------------------------------------------------
__global__ __launch_bounds__(512, 4) void attn_kernel(
    const __hip_bfloat16* __restrict__ Qm, const __hip_bfloat16* __restrict__ Km,
    const __hip_bfloat16* __restrict__ Vt, __hip_bfloat16* __restrict__ Om) {
  __shared__ __align__(16) unsigned char Kl[2][16384];  // [64 t][128 d] swizzled
  __shared__ __align__(16) unsigned char Vl[2][16384];  // [128 d][64 t] swizzled
  __shared__ __align__(16) unsigned char Pl[16384];     // per-wave 2KB bf16 [16 q][64 t]
  const int tid = threadIdx.x;
  const int lane = tid & 63, w = tid >> 6;  // w in 0..7
  const int l15 = lane & 15, lg = lane >> 4;
  const int bh = blockIdx.y, b = bh >> 4, h = bh & 15;
  const int q0 = ((int)gridDim.x - 1 - (int)blockIdx.x) * 128;  // LPT order
  const int qw = q0 + w * 16;
  const int row8 = lane >> 3;
  const int nt = (q0 >> 6) + 2;  // K/V tiles 0 .. q0/64+1

  // Q fragments (A-operand): row = l15, k = ks*32 + lg*8 .. +8
  short8 qf[4];
  const __hip_bfloat16* qbase = Qm + (size_t)(b * SEQ + qw + l15) * D_MODEL + h * DK;
#pragma unroll
  for (int ks = 0; ks < 4; ++ks) qf[ks] = *(const short8*)(qbase + ks * 32 + lg * 8);

  float m_run[4], l_run[4];
  f32x4 acc_o[8];
#pragma unroll
  for (int r = 0; r < 4; ++r) { m_run[r] = -1e30f; l_run[r] = 0.0f; }
#pragma unroll
  for (int fd = 0; fd < 8; ++fd) acc_o[fd] = (f32x4){0.f, 0.f, 0.f, 0.f};

  auto STAGE = [&](int tt) {
    unsigned char* kb = Kl[tt & 1];
    unsigned char* vb = Vl[tt & 1];
    const int t0 = tt * 64;
#pragma unroll
    for (int i = 0; i < 2; ++i) {
      const int c = w * 2 + i;
      const int row = c * 4 + lg;
      const int gcb = l15 ^ (row & 7);
      GLOAD16(Km + (size_t)(b * SEQ + t0 + row) * D_MODEL + h * DK + gcb * 8,
              kb + c * 1024);
    }
#pragma unroll
    for (int i = 0; i < 2; ++i) {
      const int c = w * 2 + i;
      const int row = c * 8 + row8;
      const int gcb = (lane & 7) ^ (row & 7);
      GLOAD16(Vt + (size_t)(bh * DK + row) * SEQ + t0 + gcb * 8, vb + c * 1024);
    }
  };

  STAGE(0);
  for (int t = 0; t < nt; ++t) {
    const int t0 = t * 64;
    if (t + 1 < nt) {
      STAGE(t + 1);  // 4 loads -> in flight across this tile's compute
      asm volatile("s_waitcnt vmcnt(4)" ::: "memory");  // tile t complete
    } else {
      asm volatile("s_waitcnt vmcnt(0)" ::: "memory");
    }
    __builtin_amdgcn_s_barrier();  // all waves: tile t in LDS; t-1 reads done
    asm volatile("" ::: "memory");
    if (t0 <= qw + 15) {
      const unsigned char* kb = Kl[t & 1];
      const unsigned char* vb = Vl[t & 1];
      // S = Q K^T  (output: row q = lg*4+r, col key = l15 within frag fn)
      f32x4 sacc[4];
#pragma unroll
      for (int fn = 0; fn < 4; ++fn) sacc[fn] = (f32x4){0.f, 0.f, 0.f, 0.f};
      __builtin_amdgcn_s_setprio(1);
#pragma unroll
      for (int ks = 0; ks < 4; ++ks) {
        const int cb = ks * 4 + lg;
#pragma unroll
        for (int fn = 0; fn < 4; ++fn) {
          const int rn = fn * 16 + l15;
          short8 kf = *(const short8*)(kb + rn * 256 + ((cb ^ (rn & 7)) << 4));
          sacc[fn] = MFMA16(qf[ks], kf, sacc[fn]);
        }
      }
      __builtin_amdgcn_s_setprio(0);
      const float scale = 0.088388347648318447f;  // 1/sqrt(128)
      float mt[4] = {-1e30f, -1e30f, -1e30f, -1e30f};
#pragma unroll
      for (int fn = 0; fn < 4; ++fn) {
        const int key = t0 + fn * 16 + l15;
#pragma unroll
        for (int r = 0; r < 4; ++r) {
          const int qg = qw + lg * 4 + r;
          float sv = sacc[fn][r] * scale;
          sv = (key <= qg) ? sv : -1e30f;
          sacc[fn][r] = sv;
          mt[r] = fmaxf(mt[r], sv);
        }
      }
#pragma unroll
      for (int r = 0; r < 4; ++r)
#pragma unroll
        for (int off = 1; off < 16; off <<= 1) mt[r] = fmaxf(mt[r], __shfl_xor(mt[r], off));
      // defer-max (T13): skip rescale when tile max is within THR of running max
      int ok = 1;
#pragma unroll
      for (int r = 0; r < 4; ++r) ok = ok && (mt[r] <= m_run[r] + 8.0f);
      const bool defer = __all(ok);
      float alpha[4];
      if (!defer) {
#pragma unroll
        for (int r = 0; r < 4; ++r) {
          const float mnew = fmaxf(m_run[r], mt[r]);
          alpha[r] = __expf(m_run[r] - mnew);
          m_run[r] = mnew;
        }
      }
      float ls[4] = {0.f, 0.f, 0.f, 0.f};
#pragma unroll
      for (int fn = 0; fn < 4; ++fn)
#pragma unroll
        for (int r = 0; r < 4; ++r) {
          const float p = __expf(sacc[fn][r] - m_run[r]);
          sacc[fn][r] = p;
          ls[r] += p;
        }
#pragma unroll
      for (int r = 0; r < 4; ++r) {
#pragma unroll
        for (int off = 1; off < 16; off <<= 1) ls[r] += __shfl_xor(ls[r], off);
        l_run[r] = (defer ? l_run[r] : l_run[r] * alpha[r]) + ls[r];
      }
      if (!defer) {
#pragma unroll
        for (int fd = 0; fd < 8; ++fd)
#pragma unroll
          for (int r = 0; r < 4; ++r) acc_o[fd][r] *= alpha[r];
      }
      // write P (bf16): row q (128B), slot = ((tt>>3)+qq+(qq>>3))&7 (2-4 way)
      unsigned char* pw = Pl + w * 2048;
#pragma unroll
      for (int fn = 0; fn < 4; ++fn) {
        const int tt = fn * 16 + l15;
#pragma unroll
        for (int r = 0; r < 4; ++r) {
          const int qq = lg * 4 + r;
          *(unsigned short*)(pw + qq * 128 +
                             ((((tt >> 3) + qq + (qq >> 3)) & 7) << 4) +
                             (tt & 7) * 2) = f2bf(sacc[fn][r]);
        }
      }
      // O += P V  (A-operand P: row q = l15, k-slot tb = ks*4+lg)
#pragma unroll
      for (int ks = 0; ks < 2; ++ks) {
        const int tb = ks * 4 + lg;
        short8 pf = *(const short8*)(Pl + w * 2048 + l15 * 128 +
                                     (((tb + l15 + (l15 >> 3)) & 7) << 4));
        const int cb = ks * 4 + lg;
        __builtin_amdgcn_s_setprio(1);
#pragma unroll
        for (int fd = 0; fd < 8; ++fd) {
          const int rv = fd * 16 + l15;
          short8 vf = *(const short8*)(vb + rv * 128 + ((cb ^ (rv & 7)) << 4));
          acc_o[fd] = MFMA16(pf, vf, acc_o[fd]);
        }
        __builtin_amdgcn_s_setprio(0);
      }
    }
    asm volatile("" ::: "memory");
    __builtin_amdgcn_s_barrier();  // all reads of buf[t&1] done before t+2 stages it
    asm volatile("" ::: "memory");
  }
#pragma unroll
  for (int r = 0; r < 4; ++r) {
    const float inv = 1.0f / l_run[r];
    const int qg = qw + lg * 4 + r;
    __hip_bfloat16* ob = Om + (size_t)(b * SEQ + qg) * D_MODEL + h * DK + l15;
#pragma unroll
    for (int fd = 0; fd < 8; ++fd)
      ob[fd * 16] = __float2bfloat16(acc_o[fd][r] * inv);
  }
}

// ---------------------------------------------------------------------------
// Workspace layout (192 MiB peak, time-shared):
//   @0   Hb (32M)  LN1 out -> later LN2 out
//   @32  Qb (32M) -\
//   @64  Kb (32M)  |-> after O-proj: FF1 full tensor (128M, 8192x8192 bf16)
//   @96  Vt (32M)  |
//   @128 AO (32M) -/
//   @160 WqT/WkT/WvT/WoT (4x8M) -> after O-proj: W1T (32M) -> after FF1: W2T (32M)
// X2 (f32 residual stream) lives in d_out itself.
// ---------------------------------------------------------------------------
extern "C" void kernel_launch(void* const* d_in, const int* in_sizes, int n_in,
                              void* d_out, int out_size, void* d_ws, size_t ws_size,
                              hipStream_t stream) {
  (void)in_sizes; (void)n_in; (void)out_size;
  const size_t MB = 1024 * 1024;
  if (ws_size < 192 * MB) return;  // diagnostic guard

  const float* x  = (const float*)d_in[0];
  const float* Wq = (const float*)d_in[1];
  const float* bq = (const float*)d_in[2];
  const float* Wk = (const float*)d_in[3];
  const float* bk = (const float*)d_in[4];
  const float* Wv = (const float*)d_in[5];
  const float* bv = (const float*)d_in[6];
  const float* Wo = (const float*)d_in[7];
  const float* bo = (const float*)d_in[8];
  const float* W1 = (const float*)d_in[9];
  const float* b1 = (const float*)d_in[10];
  const float* W2 = (const float*)d_in[11];
  const float* b2 = (const float*)d_in[12];
  const float* g1 = (const float*)d_in[13];
  const float* be1 = (const float*)d_in[14];
  const float* g2 = (const float*)d_in[15];
  const float* be2 = (const float*)d_in[16];

  char* ws = (char*)d_ws;
  __hip_bfloat16* Hb  = (__hip_bfloat16*)(ws + 0 * MB);
  __hip_bfloat16* Qb  = (__hip_bfloat16*)(ws + 32 * MB);
  __hip_bfloat16* Kb  = (__hip_bfloat16*)(ws + 64 * MB);
  __hip_bfloat16* Vtb = (__hip_bfloat16*)(ws + 96 * MB);
  __hip_bfloat16* AOb = (__hip_bfloat16*)(ws + 128 * MB);
  __hip_bfloat16* FF1 = (__hip_bfloat16*)(ws + 32 * MB);   // after O-proj, 128M
  __hip_bfloat16* WqT = (__hip_bfloat16*)(ws + 160 * MB);
  __hip_bfloat16* WkT = (__hip_bfloat16*)(ws + 168 * MB);
  __hip_bfloat16* WvT = (__hip_bfloat16*)(ws + 176 * MB);
  __hip_bfloat16* WoT = (__hip_bfloat16*)(ws + 184 * MB);
  __hip_bfloat16* W1T = (__hip_bfloat16*)(ws + 160 * MB);  // after O-proj
  __hip_bfloat16* W2T = (__hip_bfloat16*)(ws + 160 * MB);  // after FF1
  float* X2 = (float*)d_out;  // residual stream lives in d_out

  const dim3 tb(256);
  transpose_cvt_kernel<<<dim3(64, 64), tb, 0, stream>>>(Wq, WqT, 2048, 2048);
  transpose_cvt_kernel<<<dim3(64, 64), tb, 0, stream>>>(Wk, WkT, 2048, 2048);
  transpose_cvt_kernel<<<dim3(64, 64), tb, 0, stream>>>(Wv, WvT, 2048, 2048);
  transpose_cvt_kernel<<<dim3(64, 64), tb, 0, stream>>>(Wo, WoT, 2048, 2048);

  layernorm_kernel<<<MTOT, tb, 0, stream>>>(x, g1, be1, Hb);

  // QKV/O-proj: M=8192, N=2048 -> nrow=32, nbx=8 -> 256 blocks
  gemm_kernel<EPI_BF16><<<256, 512, 0, stream>>>(Hb, WqT, bq, nullptr, Qb, MTOT, 2048, 2048, 8);
  gemm_kernel<EPI_BF16><<<256, 512, 0, stream>>>(Hb, WkT, bk, nullptr, Kb, MTOT, 2048, 2048, 8);
  gemm_kernel<EPI_VT><<<256, 512, 0, stream>>>(Hb, WvT, bv, nullptr, Vtb, MTOT, 2048, 2048, 8);

  attn_kernel<<<dim3(SEQ / 128, BATCH * NUM_HEADS), dim3(512), 0, stream>>>(Qb, Kb, Vtb, AOb);

  gemm_kernel<EPI_RESID><<<256, 512, 0, stream>>>(AOb, WoT, bo, x, X2, MTOT, 2048, 2048, 8);

  layernorm_kernel<<<MTOT, tb, 0, stream>>>(X2, g2, be2, Hb);

  // FFN full-M: W1T into dead small-weight region, FF1 into dead Q/K/Vt/AO
  transpose_cvt_kernel<<<dim3(256, 64), tb, 0, stream>>>(W1, W1T, 2048, 8192);
  // FF1: M=8192, N=8192 -> nrow=32, nbx=32 -> 1024 blocks
  gemm_kernel<EPI_GELU><<<1024, 512, 0, stream>>>(Hb, W1T, b1, nullptr, FF1, MTOT, 8192, 2048, 32);
  // W2T overwrites W1T (dead after FF1)
  transpose_cvt_kernel<<<dim3(64, 256), tb, 0, stream>>>(W2, W2T, 8192, 2048);
  // FF2: M=8192, N=2048, K=8192 -> 256 blocks
  gemm_kernel<EPI_RESID><<<256, 512, 0, stream>>>(FF1, W2T, b2, X2, X2, MTOT, 2048, 8192, 8);
}

// Round 10
// 1250.807 us; speedup vs baseline: 1.2153x; 1.0189x over previous
//
#include <hip/hip_runtime.h>
#include <hip/hip_bf16.h>

#define D_MODEL 2048
#define NUM_HEADS 16
#define D_FF 8192
#define BATCH 4
#define SEQ 2048
#define DK 128
#define MTOT (BATCH * SEQ)  // 8192

typedef __attribute__((ext_vector_type(8))) short short8;
typedef __attribute__((ext_vector_type(4))) short short4v;
typedef __attribute__((ext_vector_type(4))) float f32x4;

#define MFMA16(a, b, c) __builtin_amdgcn_mfma_f32_16x16x32_bf16(a, b, c, 0, 0, 0)

#define GLOAD16(gp, lp)                                                        \
  __builtin_amdgcn_global_load_lds(                                            \
      (const __attribute__((address_space(1))) void*)(gp),                     \
      (__attribute__((address_space(3))) void*)(lp), 16, 0, 0)

static __device__ __forceinline__ unsigned short f2bf(float f) {
  return __builtin_bit_cast(unsigned short, __float2bfloat16(f));
}

// ---------------------------------------------------------------------------
// Weight convert + transpose: in f32 [K][N] -> out bf16 [N][K]
// ---------------------------------------------------------------------------
__global__ __launch_bounds__(256) void transpose_cvt_kernel(
    const float* __restrict__ in, __hip_bfloat16* __restrict__ out, int K, int N) {
  __shared__ float tile[32][33];
  const int n0 = blockIdx.x * 32, k0 = blockIdx.y * 32;
  const int tx = threadIdx.x & 31, ty = threadIdx.x >> 5;  // 32 x 8
#pragma unroll
  for (int i = 0; i < 4; ++i)
    tile[ty + i * 8][tx] = in[(size_t)(k0 + ty + i * 8) * N + n0 + tx];
  __syncthreads();
#pragma unroll
  for (int i = 0; i < 4; ++i)
    out[(size_t)(n0 + ty + i * 8) * K + k0 + tx] = __float2bfloat16(tile[tx][ty + i * 8]);
}

// ---------------------------------------------------------------------------
// LayerNorm: f32 [M][D_MODEL] -> bf16 [M][D_MODEL]
// ---------------------------------------------------------------------------
__global__ __launch_bounds__(256) void layernorm_kernel(
    const float* __restrict__ x, const float* __restrict__ g,
    const float* __restrict__ bta, __hip_bfloat16* __restrict__ out) {
  const int row = blockIdx.x;
  const int tid = threadIdx.x;
  const float* xr = x + (size_t)row * D_MODEL;
  float4 v0 = *(const float4*)(xr + tid * 8);
  float4 v1 = *(const float4*)(xr + tid * 8 + 4);
  float s = v0.x + v0.y + v0.z + v0.w + v1.x + v1.y + v1.z + v1.w;
  float q = v0.x * v0.x + v0.y * v0.y + v0.z * v0.z + v0.w * v0.w +
            v1.x * v1.x + v1.y * v1.y + v1.z * v1.z + v1.w * v1.w;
#pragma unroll
  for (int off = 1; off < 64; off <<= 1) {
    s += __shfl_xor(s, off);
    q += __shfl_xor(q, off);
  }
  __shared__ float rs[4], rq[4];
  if ((tid & 63) == 0) {
    rs[tid >> 6] = s;
    rq[tid >> 6] = q;
  }
  __syncthreads();
  s = rs[0] + rs[1] + rs[2] + rs[3];
  q = rq[0] + rq[1] + rq[2] + rq[3];
  const float mu = s * (1.0f / D_MODEL);
  const float var = q * (1.0f / D_MODEL) - mu * mu;
  const float rstd = rsqrtf(var + 1e-5f);
  float4 g0 = *(const float4*)(g + tid * 8);
  float4 g1 = *(const float4*)(g + tid * 8 + 4);
  float4 b0 = *(const float4*)(bta + tid * 8);
  float4 b1 = *(const float4*)(bta + tid * 8 + 4);
  short8 o;
  o[0] = (short)f2bf((v0.x - mu) * rstd * g0.x + b0.x);
  o[1] = (short)f2bf((v0.y - mu) * rstd * g0.y + b0.y);
  o[2] = (short)f2bf((v0.z - mu) * rstd * g0.z + b0.z);
  o[3] = (short)f2bf((v0.w - mu) * rstd * g0.w + b0.w);
  o[4] = (short)f2bf((v1.x - mu) * rstd * g1.x + b1.x);
  o[5] = (short)f2bf((v1.y - mu) * rstd * g1.y + b1.y);
  o[6] = (short)f2bf((v1.z - mu) * rstd * g1.z + b1.z);
  o[7] = (short)f2bf((v1.w - mu) * rstd * g1.w + b1.w);
  *(short8*)(out + (size_t)row * D_MODEL + tid * 8) = o;
}

// ---------------------------------------------------------------------------
// GEMM v4: C[M][N] = A[M][K] @ Bt[N][K]^T (+bias, epilogue variants)
// 256x256 tile, BK=64, 8 waves (2Mx4N), double-buffered LDS (128 KiB).
// Counted vmcnt(8): 2 tiles in flight, never drained mid-loop.
// XCD decode gives each XCD a concurrent 4r x 8c window:
//   x=d&7; i=d>>3; c=(i&7)+8*(i>>5); r=x+8*((i>>3)&3)
// -> per XCD/K-tile: 4 A-panels (8-way shared) + 8 B-panels (4-way shared)
//    = 384 KB unique vs 1056 KB with the old c=qd%nbx decode (FF1 delivery-
//    bound fix). Each XCD touches only 4 A-panels total (L2-resident).
// Requires nrow=32 (M=8192) and nbx in {8,32} - true for all 6 GEMMs.
// ---------------------------------------------------------------------------
enum { EPI_BF16 = 0, EPI_VT = 1, EPI_RESID = 2, EPI_GELU = 3 };

template <int EPI>
__global__ __launch_bounds__(512, 2) void gemm_kernel(
    const __hip_bfloat16* __restrict__ A, const __hip_bfloat16* __restrict__ Bt,
    const float* __restrict__ bias, const float* __restrict__ resid,
    void* __restrict__ outv, int M, int N, int K) {
  __shared__ __align__(16) unsigned char lds[2][65536];  // [dbuf][A 32K | B 32K]
  const int tid = threadIdx.x;
  const int lane = tid & 63, w = tid >> 6;  // 8 waves
  const int l15 = lane & 15, lg = lane >> 4;
  const int d = blockIdx.x;
  const int x = d & 7;   // XCD (round-robin dispatch)
  const int i = d >> 3;  // within-XCD index
  const int cC = (i & 7) + 8 * (i >> 5);
  const int rC = x + 8 * ((i >> 3) & 3);
  const int m0 = rC * 256, n0 = cC * 256;
  const int wm = (w >> 2) * 128, wn = (w & 3) * 64;

  f32x4 acc[8][4] = {};

  const int row8 = lane >> 3;        // 0..7 (row within 8-row chunk)
  const int g8 = (lane & 7) ^ row8;  // pre-swizzled source 16B-block

  auto STAGE = [&](int tt) {
    unsigned char* db = lds[tt & 1];
    const size_t ko = (size_t)tt * 64;
#pragma unroll
    for (int ii = 0; ii < 4; ++ii) {
      const int c = w * 4 + ii;  // A chunk 0..31 (8 rows x 128B each)
      const int row = c * 8 + row8;
      GLOAD16(A + (size_t)(m0 + row) * K + ko + g8 * 8, db + c * 1024);
    }
#pragma unroll
    for (int ii = 0; ii < 4; ++ii) {
      const int c = w * 4 + ii;  // B chunk 0..31
      const int row = c * 8 + row8;
      GLOAD16(Bt + (size_t)(n0 + row) * K + ko + g8 * 8, db + 32768 + c * 1024);
    }
  };
  auto COMPUTE = [&](int tt) {
    const unsigned char* db = lds[tt & 1];
#pragma unroll
    for (int ks = 0; ks < 2; ++ks) {
      const int cb = ks * 4 + lg;
      short8 af[8], bf[4];
#pragma unroll
      for (int f = 0; f < 8; ++f) {
        const int ra = wm + f * 16 + l15;
        af[f] = *(const short8*)(db + ra * 128 + ((cb ^ (ra & 7)) << 4));
      }
#pragma unroll
      for (int f = 0; f < 4; ++f) {
        const int rb = wn + f * 16 + l15;
        bf[f] = *(const short8*)(db + 32768 + rb * 128 + ((cb ^ (rb & 7)) << 4));
      }
      __builtin_amdgcn_s_setprio(1);
#pragma unroll
      for (int fi = 0; fi < 8; ++fi)
#pragma unroll
        for (int fj = 0; fj < 4; ++fj)
          acc[fi][fj] = MFMA16(af[fi], bf[fj], acc[fi][fj]);
      __builtin_amdgcn_s_setprio(0);
    }
  };

  const int nt = K >> 6;  // K-tiles of 64
  STAGE(0);
  STAGE(1);
  for (int t = 0; t < nt; ++t) {
    if (t < nt - 1)
      asm volatile("s_waitcnt vmcnt(8)" ::: "memory");  // tile t fully landed
    else
      asm volatile("s_waitcnt vmcnt(0)" ::: "memory");
    __builtin_amdgcn_s_barrier();  // all waves' tile-t loads in LDS
    COMPUTE(t);
    asm volatile("" ::: "memory");
    __builtin_amdgcn_s_barrier();  // all reads of buf t&1 done
    if (t + 2 < nt) STAGE(t + 2);  // overwrites buf t&1
  }

#pragma unroll
  for (int fi = 0; fi < 8; ++fi) {
#pragma unroll
    for (int fj = 0; fj < 4; ++fj) {
      const int mb = m0 + wm + fi * 16 + lg * 4;
      const int n = n0 + wn + fj * 16 + l15;
      const float bv = bias ? bias[n] : 0.0f;
      if constexpr (EPI == EPI_VT) {
        // out bf16 [B][H][DK][SEQ]; m -> (b, s), n -> (h, d)
        const int bb = mb >> 11, ss = mb & (SEQ - 1);
        const int hh = n >> 7, dd = n & (DK - 1);
        short4v pk;
#pragma unroll
        for (int r = 0; r < 4; ++r) pk[r] = (short)f2bf(acc[fi][fj][r] + bv);
        __hip_bfloat16* o = (__hip_bfloat16*)outv;
        *(short4v*)(o + ((size_t)((bb * NUM_HEADS + hh) * DK + dd)) * SEQ + ss) = pk;
      } else {
#pragma unroll
        for (int r = 0; r < 4; ++r) {
          const int m = mb + r;
          const float v = acc[fi][fj][r] + bv;
          if constexpr (EPI == EPI_BF16) {
            ((__hip_bfloat16*)outv)[(size_t)m * N + n] = __float2bfloat16(v);
          } else if constexpr (EPI == EPI_GELU) {
            const float ge = 0.5f * v * (1.0f + erff(v * 0.70710678118654752f));
            ((__hip_bfloat16*)outv)[(size_t)m * N + n] = __float2bfloat16(ge);
          } else {  // EPI_RESID (resid may alias outv: same-element read->write)
            ((float*)outv)[(size_t)m * N + n] = resid[(size_t)m * N + n] + v;
          }
        }
      }
    }
  }
}

// ---------------------------------------------------------------------------
// Flash attention (causal). Grid: (SEQ/128, B*H). 8 waves, 16 q-rows each.
// LPT dispatch; dbuf K/V stage-ahead + counted vmcnt(4); bf16 P-scratch with
// conflict-reduced slot = ((tt>>3)+qq+(qq>>3))&7; defer-max; setprio. 80KB.
// ---------------------------------------------------------------------------
__global__ __launch_bounds__(512, 4) void attn_kernel(
    const __hip_bfloat16* __restrict__ Qm, const __hip_bfloat16* __restrict__ Km,
    const __hip_bfloat16* __restrict__ Vt, __hip_bfloat16* __restrict__ Om) {
  __shared__ __align__(16) unsigned char Kl[2][16384];  // [64 t][128 d] swizzled
  __shared__ __align__(16) unsigned char Vl[2][16384];  // [128 d][64 t] swizzled
  __shared__ __align__(16) unsigned char Pl[16384];     // per-wave 2KB bf16 [16 q][64 t]
  const int tid = threadIdx.x;
  const int lane = tid & 63, w = tid >> 6;  // w in 0..7
  const int l15 = lane & 15, lg = lane >> 4;
  const int bh = blockIdx.y, b = bh >> 4, h = bh & 15;
  const int q0 = ((int)gridDim.x - 1 - (int)blockIdx.x) * 128;  // LPT order
  const int qw = q0 + w * 16;
  const int row8 = lane >> 3;
  const int nt = (q0 >> 6) + 2;  // K/V tiles 0 .. q0/64+1

  // Q fragments (A-operand): row = l15, k = ks*32 + lg*8 .. +8
  short8 qf[4];
  const __hip_bfloat16* qbase = Qm + (size_t)(b * SEQ + qw + l15) * D_MODEL + h * DK;
#pragma unroll
  for (int ks = 0; ks < 4; ++ks) qf[ks] = *(const short8*)(qbase + ks * 32 + lg * 8);

  float m_run[4], l_run[4];
  f32x4 acc_o[8];
#pragma unroll
  for (int r = 0; r < 4; ++r) { m_run[r] = -1e30f; l_run[r] = 0.0f; }
#pragma unroll
  for (int fd = 0; fd < 8; ++fd) acc_o[fd] = (f32x4){0.f, 0.f, 0.f, 0.f};

  auto STAGE = [&](int tt) {
    unsigned char* kb = Kl[tt & 1];
    unsigned char* vb = Vl[tt & 1];
    const int t0 = tt * 64;
#pragma unroll
    for (int i = 0; i < 2; ++i) {
      const int c = w * 2 + i;
      const int row = c * 4 + lg;
      const int gcb = l15 ^ (row & 7);
      GLOAD16(Km + (size_t)(b * SEQ + t0 + row) * D_MODEL + h * DK + gcb * 8,
              kb + c * 1024);
    }
#pragma unroll
    for (int i = 0; i < 2; ++i) {
      const int c = w * 2 + i;
      const int row = c * 8 + row8;
      const int gcb = (lane & 7) ^ (row & 7);
      GLOAD16(Vt + (size_t)(bh * DK + row) * SEQ + t0 + gcb * 8, vb + c * 1024);
    }
  };

  STAGE(0);
  for (int t = 0; t < nt; ++t) {
    const int t0 = t * 64;
    if (t + 1 < nt) {
      STAGE(t + 1);  // 4 loads -> in flight across this tile's compute
      asm volatile("s_waitcnt vmcnt(4)" ::: "memory");  // tile t complete
    } else {
      asm volatile("s_waitcnt vmcnt(0)" ::: "memory");
    }
    __builtin_amdgcn_s_barrier();  // all waves: tile t in LDS; t-1 reads done
    asm volatile("" ::: "memory");
    if (t0 <= qw + 15) {
      const unsigned char* kb = Kl[t & 1];
      const unsigned char* vb = Vl[t & 1];
      // S = Q K^T  (output: row q = lg*4+r, col key = l15 within frag fn)
      f32x4 sacc[4];
#pragma unroll
      for (int fn = 0; fn < 4; ++fn) sacc[fn] = (f32x4){0.f, 0.f, 0.f, 0.f};
      __builtin_amdgcn_s_setprio(1);
#pragma unroll
      for (int ks = 0; ks < 4; ++ks) {
        const int cb = ks * 4 + lg;
#pragma unroll
        for (int fn = 0; fn < 4; ++fn) {
          const int rn = fn * 16 + l15;
          short8 kf = *(const short8*)(kb + rn * 256 + ((cb ^ (rn & 7)) << 4));
          sacc[fn] = MFMA16(qf[ks], kf, sacc[fn]);
        }
      }
      __builtin_amdgcn_s_setprio(0);
      const float scale = 0.088388347648318447f;  // 1/sqrt(128)
      float mt[4] = {-1e30f, -1e30f, -1e30f, -1e30f};
#pragma unroll
      for (int fn = 0; fn < 4; ++fn) {
        const int key = t0 + fn * 16 + l15;
#pragma unroll
        for (int r = 0; r < 4; ++r) {
          const int qg = qw + lg * 4 + r;
          float sv = sacc[fn][r] * scale;
          sv = (key <= qg) ? sv : -1e30f;
          sacc[fn][r] = sv;
          mt[r] = fmaxf(mt[r], sv);
        }
      }
#pragma unroll
      for (int r = 0; r < 4; ++r)
#pragma unroll
        for (int off = 1; off < 16; off <<= 1) mt[r] = fmaxf(mt[r], __shfl_xor(mt[r], off));
      // defer-max (T13): skip rescale when tile max is within THR of running max
      int ok = 1;
#pragma unroll
      for (int r = 0; r < 4; ++r) ok = ok && (mt[r] <= m_run[r] + 8.0f);
      const bool defer = __all(ok);
      float alpha[4];
      if (!defer) {
#pragma unroll
        for (int r = 0; r < 4; ++r) {
          const float mnew = fmaxf(m_run[r], mt[r]);
          alpha[r] = __expf(m_run[r] - mnew);
          m_run[r] = mnew;
        }
      }
      float ls[4] = {0.f, 0.f, 0.f, 0.f};
#pragma unroll
      for (int fn = 0; fn < 4; ++fn)
#pragma unroll
        for (int r = 0; r < 4; ++r) {
          const float p = __expf(sacc[fn][r] - m_run[r]);
          sacc[fn][r] = p;
          ls[r] += p;
        }
#pragma unroll
      for (int r = 0; r < 4; ++r) {
#pragma unroll
        for (int off = 1; off < 16; off <<= 1) ls[r] += __shfl_xor(ls[r], off);
        l_run[r] = (defer ? l_run[r] : l_run[r] * alpha[r]) + ls[r];
      }
      if (!defer) {
#pragma unroll
        for (int fd = 0; fd < 8; ++fd)
#pragma unroll
          for (int r = 0; r < 4; ++r) acc_o[fd][r] *= alpha[r];
      }
      // write P (bf16): row q (128B), slot = ((tt>>3)+qq+(qq>>3))&7 (2-4 way)
      unsigned char* pw = Pl + w * 2048;
#pragma unroll
      for (int fn = 0; fn < 4; ++fn) {
        const int tt = fn * 16 + l15;
#pragma unroll
        for (int r = 0; r < 4; ++r) {
          const int qq = lg * 4 + r;
          *(unsigned short*)(pw + qq * 128 +
                             ((((tt >> 3) + qq + (qq >> 3)) & 7) << 4) +
                             (tt & 7) * 2) = f2bf(sacc[fn][r]);
        }
      }
      // O += P V  (A-operand P: row q = l15, k-slot tb = ks*4+lg)
#pragma unroll
      for (int ks = 0; ks < 2; ++ks) {
        const int tb = ks * 4 + lg;
        short8 pf = *(const short8*)(Pl + w * 2048 + l15 * 128 +
                                     (((tb + l15 + (l15 >> 3)) & 7) << 4));
        const int cb = ks * 4 + lg;
        __builtin_amdgcn_s_setprio(1);
#pragma unroll
        for (int fd = 0; fd < 8; ++fd) {
          const int rv = fd * 16 + l15;
          short8 vf = *(const short8*)(vb + rv * 128 + ((cb ^ (rv & 7)) << 4));
          acc_o[fd] = MFMA16(pf, vf, acc_o[fd]);
        }
        __builtin_amdgcn_s_setprio(0);
      }
    }
    asm volatile("" ::: "memory");
    __builtin_amdgcn_s_barrier();  // all reads of buf[t&1] done before t+2 stages it
    asm volatile("" ::: "memory");
  }
#pragma unroll
  for (int r = 0; r < 4; ++r) {
    const float inv = 1.0f / l_run[r];
    const int qg = qw + lg * 4 + r;
    __hip_bfloat16* ob = Om + (size_t)(b * SEQ + qg) * D_MODEL + h * DK + l15;
#pragma unroll
    for (int fd = 0; fd < 8; ++fd)
      ob[fd * 16] = __float2bfloat16(acc_o[fd][r] * inv);
  }
}

// ---------------------------------------------------------------------------
// Workspace layout (192 MiB peak, time-shared):
//   @0   Hb (32M)  LN1 out -> later LN2 out
//   @32  Qb (32M) -\
//   @64  Kb (32M)  |-> after O-proj: FF1 full tensor (128M, 8192x8192 bf16)
//   @96  Vt (32M)  |
//   @128 AO (32M) -/
//   @160 WqT/WkT/WvT/WoT (4x8M) -> after O-proj: W1T (32M) -> after FF1: W2T (32M)
// X2 (f32 residual stream) lives in d_out itself.
// ---------------------------------------------------------------------------
extern "C" void kernel_launch(void* const* d_in, const int* in_sizes, int n_in,
                              void* d_out, int out_size, void* d_ws, size_t ws_size,
                              hipStream_t stream) {
  (void)in_sizes; (void)n_in; (void)out_size;
  const size_t MB = 1024 * 1024;
  if (ws_size < 192 * MB) return;  // diagnostic guard

  const float* x  = (const float*)d_in[0];
  const float* Wq = (const float*)d_in[1];
  const float* bq = (const float*)d_in[2];
  const float* Wk = (const float*)d_in[3];
  const float* bk = (const float*)d_in[4];
  const float* Wv = (const float*)d_in[5];
  const float* bv = (const float*)d_in[6];
  const float* Wo = (const float*)d_in[7];
  const float* bo = (const float*)d_in[8];
  const float* W1 = (const float*)d_in[9];
  const float* b1 = (const float*)d_in[10];
  const float* W2 = (const float*)d_in[11];
  const float* b2 = (const float*)d_in[12];
  const float* g1 = (const float*)d_in[13];
  const float* be1 = (const float*)d_in[14];
  const float* g2 = (const float*)d_in[15];
  const float* be2 = (const float*)d_in[16];

  char* ws = (char*)d_ws;
  __hip_bfloat16* Hb  = (__hip_bfloat16*)(ws + 0 * MB);
  __hip_bfloat16* Qb  = (__hip_bfloat16*)(ws + 32 * MB);
  __hip_bfloat16* Kb  = (__hip_bfloat16*)(ws + 64 * MB);
  __hip_bfloat16* Vtb = (__hip_bfloat16*)(ws + 96 * MB);
  __hip_bfloat16* AOb = (__hip_bfloat16*)(ws + 128 * MB);
  __hip_bfloat16* FF1 = (__hip_bfloat16*)(ws + 32 * MB);   // after O-proj, 128M
  __hip_bfloat16* WqT = (__hip_bfloat16*)(ws + 160 * MB);
  __hip_bfloat16* WkT = (__hip_bfloat16*)(ws + 168 * MB);
  __hip_bfloat16* WvT = (__hip_bfloat16*)(ws + 176 * MB);
  __hip_bfloat16* WoT = (__hip_bfloat16*)(ws + 184 * MB);
  __hip_bfloat16* W1T = (__hip_bfloat16*)(ws + 160 * MB);  // after O-proj
  __hip_bfloat16* W2T = (__hip_bfloat16*)(ws + 160 * MB);  // after FF1
  float* X2 = (float*)d_out;  // residual stream lives in d_out

  const dim3 tb(256);
  transpose_cvt_kernel<<<dim3(64, 64), tb, 0, stream>>>(Wq, WqT, 2048, 2048);
  transpose_cvt_kernel<<<dim3(64, 64), tb, 0, stream>>>(Wk, WkT, 2048, 2048);
  transpose_cvt_kernel<<<dim3(64, 64), tb, 0, stream>>>(Wv, WvT, 2048, 2048);
  transpose_cvt_kernel<<<dim3(64, 64), tb, 0, stream>>>(Wo, WoT, 2048, 2048);

  layernorm_kernel<<<MTOT, tb, 0, stream>>>(x, g1, be1, Hb);

  // QKV/O-proj: M=8192, N=2048 -> 256 blocks (XCD window 4r x 8c)
  gemm_kernel<EPI_BF16><<<256, 512, 0, stream>>>(Hb, WqT, bq, nullptr, Qb, MTOT, 2048, 2048);
  gemm_kernel<EPI_BF16><<<256, 512, 0, stream>>>(Hb, WkT, bk, nullptr, Kb, MTOT, 2048, 2048);
  gemm_kernel<EPI_VT><<<256, 512, 0, stream>>>(Hb, WvT, bv, nullptr, Vtb, MTOT, 2048, 2048);

  attn_kernel<<<dim3(SEQ / 128, BATCH * NUM_HEADS), dim3(512), 0, stream>>>(Qb, Kb, Vtb, AOb);

  gemm_kernel<EPI_RESID><<<256, 512, 0, stream>>>(AOb, WoT, bo, x, X2, MTOT, 2048, 2048);

  layernorm_kernel<<<MTOT, tb, 0, stream>>>(X2, g2, be2, Hb);

  // FFN full-M: W1T into dead small-weight region, FF1 into dead Q/K/Vt/AO
  transpose_cvt_kernel<<<dim3(256, 64), tb, 0, stream>>>(W1, W1T, 2048, 8192);
  // FF1: M=8192, N=8192 -> 1024 blocks
  gemm_kernel<EPI_GELU><<<1024, 512, 0, stream>>>(Hb, W1T, b1, nullptr, FF1, MTOT, 8192, 2048);
  // W2T overwrites W1T (dead after FF1)
  transpose_cvt_kernel<<<dim3(64, 256), tb, 0, stream>>>(W2, W2T, 8192, 2048);
  // FF2: M=8192, N=2048, K=8192 -> 256 blocks
  gemm_kernel<EPI_RESID><<<256, 512, 0, stream>>>(FF1, W2T, b2, X2, X2, MTOT, 2048, 8192);
}

// Round 11
// 1225.845 us; speedup vs baseline: 1.2400x; 1.0204x over previous
//
#include <hip/hip_runtime.h>
#include <hip/hip_bf16.h>

#define D_MODEL 2048
#define NUM_HEADS 16
#define D_FF 8192
#define BATCH 4
#define SEQ 2048
#define DK 128
#define MTOT (BATCH * SEQ)  // 8192

typedef __attribute__((ext_vector_type(8))) short short8;
typedef __attribute__((ext_vector_type(4))) short short4v;
typedef __attribute__((ext_vector_type(4))) float f32x4;

#define MFMA16(a, b, c) __builtin_amdgcn_mfma_f32_16x16x32_bf16(a, b, c, 0, 0, 0)

#define GLOAD16(gp, lp)                                                        \
  __builtin_amdgcn_global_load_lds(                                            \
      (const __attribute__((address_space(1))) void*)(gp),                     \
      (__attribute__((address_space(3))) void*)(lp), 16, 0, 0)

static __device__ __forceinline__ unsigned short f2bf(float f) {
  return __builtin_bit_cast(unsigned short, __float2bfloat16(f));
}

// ---------------------------------------------------------------------------
// Weight convert + transpose: in f32 [K][N] -> out bf16 [N][K]
// ---------------------------------------------------------------------------
__global__ __launch_bounds__(256) void transpose_cvt_kernel(
    const float* __restrict__ in, __hip_bfloat16* __restrict__ out, int K, int N) {
  __shared__ float tile[32][33];
  const int n0 = blockIdx.x * 32, k0 = blockIdx.y * 32;
  const int tx = threadIdx.x & 31, ty = threadIdx.x >> 5;  // 32 x 8
#pragma unroll
  for (int i = 0; i < 4; ++i)
    tile[ty + i * 8][tx] = in[(size_t)(k0 + ty + i * 8) * N + n0 + tx];
  __syncthreads();
#pragma unroll
  for (int i = 0; i < 4; ++i)
    out[(size_t)(n0 + ty + i * 8) * K + k0 + tx] = __float2bfloat16(tile[tx][ty + i * 8]);
}

// ---------------------------------------------------------------------------
// LayerNorm: f32 [M][D_MODEL] -> bf16 [M][D_MODEL]
// ---------------------------------------------------------------------------
__global__ __launch_bounds__(256) void layernorm_kernel(
    const float* __restrict__ x, const float* __restrict__ g,
    const float* __restrict__ bta, __hip_bfloat16* __restrict__ out) {
  const int row = blockIdx.x;
  const int tid = threadIdx.x;
  const float* xr = x + (size_t)row * D_MODEL;
  float4 v0 = *(const float4*)(xr + tid * 8);
  float4 v1 = *(const float4*)(xr + tid * 8 + 4);
  float s = v0.x + v0.y + v0.z + v0.w + v1.x + v1.y + v1.z + v1.w;
  float q = v0.x * v0.x + v0.y * v0.y + v0.z * v0.z + v0.w * v0.w +
            v1.x * v1.x + v1.y * v1.y + v1.z * v1.z + v1.w * v1.w;
#pragma unroll
  for (int off = 1; off < 64; off <<= 1) {
    s += __shfl_xor(s, off);
    q += __shfl_xor(q, off);
  }
  __shared__ float rs[4], rq[4];
  if ((tid & 63) == 0) {
    rs[tid >> 6] = s;
    rq[tid >> 6] = q;
  }
  __syncthreads();
  s = rs[0] + rs[1] + rs[2] + rs[3];
  q = rq[0] + rq[1] + rq[2] + rq[3];
  const float mu = s * (1.0f / D_MODEL);
  const float var = q * (1.0f / D_MODEL) - mu * mu;
  const float rstd = rsqrtf(var + 1e-5f);
  float4 g0 = *(const float4*)(g + tid * 8);
  float4 g1 = *(const float4*)(g + tid * 8 + 4);
  float4 b0 = *(const float4*)(bta + tid * 8);
  float4 b1 = *(const float4*)(bta + tid * 8 + 4);
  short8 o;
  o[0] = (short)f2bf((v0.x - mu) * rstd * g0.x + b0.x);
  o[1] = (short)f2bf((v0.y - mu) * rstd * g0.y + b0.y);
  o[2] = (short)f2bf((v0.z - mu) * rstd * g0.z + b0.z);
  o[3] = (short)f2bf((v0.w - mu) * rstd * g0.w + b0.w);
  o[4] = (short)f2bf((v1.x - mu) * rstd * g1.x + b1.x);
  o[5] = (short)f2bf((v1.y - mu) * rstd * g1.y + b1.y);
  o[6] = (short)f2bf((v1.z - mu) * rstd * g1.z + b1.z);
  o[7] = (short)f2bf((v1.w - mu) * rstd * g1.w + b1.w);
  *(short8*)(out + (size_t)row * D_MODEL + tid * 8) = o;
}

// ---------------------------------------------------------------------------
// GEMM v5: 256x256 tile, BK=64, 8 waves (2Mx4N), double-buffered LDS (128K).
// 8-phase-style schedule (T3+T4): per K-tile 4 phases x {stage / ds_read /
// barrier / lgkmcnt(0) / 16 MFMA / barrier}; single vmcnt(7) at P3 before the
// end-barrier (counted, never drained mid-loop).
// Race proof: B region + A-quarter0 of tile t are dead after t.P0's end-
// barrier; A-quarter q dead after t.Pq's end-barrier (per-wave ds_reads
// retired by that phase's lgkmcnt(0), certified cross-wave by the barrier).
// Stage(t+2) -> buf[t&1] is distributed: P1:{B0,B1,A-q0}, P2:{B2,B3,A-q1},
// P3:{A-q2}, (t+1).P0:{A-q3} - each after its region's death barrier.
// FIFO ledger per wave: at t.P3 vmcnt, outstanding = t+2's 7 loads ->
// vmcnt(7) retires all of t+1's 8 loads before the end-barrier, making
// t+1.P0's ds_reads cross-wave safe. Tail: vmcnt(0) when t+2 >= nt.
// XCD decode (4r x 8c concurrent window per XCD) as round 10.
// ---------------------------------------------------------------------------
enum { EPI_BF16 = 0, EPI_VT = 1, EPI_RESID = 2, EPI_GELU = 3 };

#define AF_MFMA_PHASE(FI0)                                                     \
  {                                                                            \
    const int raA = wm + (FI0) * 16 + l15;                                     \
    const int raB = wm + ((FI0) + 1) * 16 + l15;                               \
    short8 aA0 = *(const short8*)(db + raA * 128 + ((lg ^ (raA & 7)) << 4));   \
    short8 aB0 = *(const short8*)(db + raB * 128 + ((lg ^ (raB & 7)) << 4));   \
    short8 aA1 =                                                               \
        *(const short8*)(db + raA * 128 + (((4 + lg) ^ (raA & 7)) << 4));      \
    short8 aB1 =                                                               \
        *(const short8*)(db + raB * 128 + (((4 + lg) ^ (raB & 7)) << 4));      \
    __builtin_amdgcn_s_barrier();                                              \
    asm volatile("s_waitcnt lgkmcnt(0)" ::: "memory");                         \
    __builtin_amdgcn_sched_barrier(0);                                         \
    __builtin_amdgcn_s_setprio(1);                                             \
    _Pragma("unroll") for (int fj = 0; fj < 4; ++fj)                           \
        acc[FI0][fj] = MFMA16(aA0, bf0[fj], acc[FI0][fj]);                     \
    _Pragma("unroll") for (int fj = 0; fj < 4; ++fj)                           \
        acc[(FI0) + 1][fj] = MFMA16(aB0, bf0[fj], acc[(FI0) + 1][fj]);         \
    _Pragma("unroll") for (int fj = 0; fj < 4; ++fj)                           \
        acc[FI0][fj] = MFMA16(aA1, bf1[fj], acc[FI0][fj]);                     \
    _Pragma("unroll") for (int fj = 0; fj < 4; ++fj)                           \
        acc[(FI0) + 1][fj] = MFMA16(aB1, bf1[fj], acc[(FI0) + 1][fj]);         \
    __builtin_amdgcn_s_setprio(0);                                             \
  }

template <int EPI>
__global__ __launch_bounds__(512, 2) void gemm_kernel(
    const __hip_bfloat16* __restrict__ A, const __hip_bfloat16* __restrict__ Bt,
    const float* __restrict__ bias, const float* __restrict__ resid,
    void* __restrict__ outv, int M, int N, int K) {
  __shared__ __align__(16) unsigned char lds[2][65536];  // [dbuf][A 32K | B 32K]
  const int tid = threadIdx.x;
  const int lane = tid & 63, w = tid >> 6;  // 8 waves
  const int l15 = lane & 15, lg = lane >> 4;
  const int d = blockIdx.x;
  const int x = d & 7;   // XCD (round-robin dispatch)
  const int i = d >> 3;  // within-XCD index
  const int cC = (i & 7) + 8 * (i >> 5);
  const int rC = x + 8 * ((i >> 3) & 3);
  const int m0 = rC * 256, n0 = cC * 256;
  const int wm = (w >> 2) * 128, wn = (w & 3) * 64;

  f32x4 acc[8][4] = {};

  const int row8 = lane >> 3;        // 0..7 (row within 8-row chunk)
  const int g8 = (lane & 7) ^ row8;  // pre-swizzled source 16B-block
  const int wa = (w & 3) + ((w >> 2) * 16);  // A-chunk base for this wave

  auto stA = [&](int tt, int c) {
    GLOAD16(A + (size_t)(m0 + c * 8 + row8) * K + (size_t)tt * 64 + g8 * 8,
            lds[tt & 1] + c * 1024);
  };
  auto stB = [&](int tt, int c) {
    GLOAD16(Bt + (size_t)(n0 + c * 8 + row8) * K + (size_t)tt * 64 + g8 * 8,
            lds[tt & 1] + 32768 + c * 1024);
  };

  const int nt = K >> 6;  // K-tiles of 64

  // prologue: tile0 all 8 loads, tile1 first 7 (A4 of tile1 staged at t0.P0)
  stB(0, w); stB(0, 8 + w); stA(0, wa);
  stB(0, 16 + w); stB(0, 24 + w); stA(0, wa + 4);
  stA(0, wa + 8); stA(0, wa + 12);
  stB(1, w); stB(1, 8 + w); stA(1, wa);
  stB(1, 16 + w); stB(1, 24 + w); stA(1, wa + 4);
  stA(1, wa + 8);
  asm volatile("s_waitcnt vmcnt(7)" ::: "memory");  // tile0 fully in LDS
  __builtin_amdgcn_s_barrier();

  for (int t = 0; t < nt; ++t) {
    const unsigned char* db = lds[t & 1];
    const bool s1 = (t + 1 < nt), s2 = (t + 2 < nt);
    short8 bf0[4], bf1[4];
    // ---------------- P0: bf(all) + af fi0,1 ----------------
    if (s1) stA(t + 1, wa + 12);  // A-q3 of t+1 (dead since (t-1).P3)
#pragma unroll
    for (int f = 0; f < 4; ++f) {
      const int rb = wn + f * 16 + l15;
      bf0[f] = *(const short8*)(db + 32768 + rb * 128 + ((lg ^ (rb & 7)) << 4));
      bf1[f] =
          *(const short8*)(db + 32768 + rb * 128 + (((4 + lg) ^ (rb & 7)) << 4));
    }
    AF_MFMA_PHASE(0)
    __builtin_amdgcn_s_barrier();  // end P0: B + A-q0 of tile t dead
    // ---------------- P1: af fi2,3 ----------------
    if (s2) { stB(t + 2, w); stB(t + 2, 8 + w); stA(t + 2, wa); }
    AF_MFMA_PHASE(2)
    __builtin_amdgcn_s_barrier();  // end P1: A-q1 dead
    // ---------------- P2: af fi4,5 ----------------
    if (s2) { stB(t + 2, 16 + w); stB(t + 2, 24 + w); stA(t + 2, wa + 4); }
    AF_MFMA_PHASE(4)
    __builtin_amdgcn_s_barrier();  // end P2: A-q2 dead
    // ---------------- P3: af fi6,7 ----------------
    if (s2) stA(t + 2, wa + 8);
    AF_MFMA_PHASE(6)
    if (s2)
      asm volatile("s_waitcnt vmcnt(7)" ::: "memory");  // t+1's 8 retired
    else
      asm volatile("s_waitcnt vmcnt(0)" ::: "memory");
    __builtin_amdgcn_s_barrier();  // end P3: next tile's reads now safe
  }

#pragma unroll
  for (int fi = 0; fi < 8; ++fi) {
#pragma unroll
    for (int fj = 0; fj < 4; ++fj) {
      const int mb = m0 + wm + fi * 16 + lg * 4;
      const int n = n0 + wn + fj * 16 + l15;
      const float bv = bias ? bias[n] : 0.0f;
      if constexpr (EPI == EPI_VT) {
        // out bf16 [B][H][DK][SEQ]; m -> (b, s), n -> (h, d)
        const int bb = mb >> 11, ss = mb & (SEQ - 1);
        const int hh = n >> 7, dd = n & (DK - 1);
        short4v pk;
#pragma unroll
        for (int r = 0; r < 4; ++r) pk[r] = (short)f2bf(acc[fi][fj][r] + bv);
        __hip_bfloat16* o = (__hip_bfloat16*)outv;
        *(short4v*)(o + ((size_t)((bb * NUM_HEADS + hh) * DK + dd)) * SEQ + ss) = pk;
      } else {
#pragma unroll
        for (int r = 0; r < 4; ++r) {
          const int m = mb + r;
          const float v = acc[fi][fj][r] + bv;
          if constexpr (EPI == EPI_BF16) {
            ((__hip_bfloat16*)outv)[(size_t)m * N + n] = __float2bfloat16(v);
          } else if constexpr (EPI == EPI_GELU) {
            const float ge = 0.5f * v * (1.0f + erff(v * 0.70710678118654752f));
            ((__hip_bfloat16*)outv)[(size_t)m * N + n] = __float2bfloat16(ge);
          } else {  // EPI_RESID (resid may alias outv: same-element read->write)
            ((float*)outv)[(size_t)m * N + n] = resid[(size_t)m * N + n] + v;
          }
        }
      }
    }
  }
}

// ---------------------------------------------------------------------------
// Flash attention (causal). Grid: (SEQ/128, B*H). 8 waves, 16 q-rows each.
// LPT dispatch; dbuf K/V stage-ahead + counted vmcnt(4); bf16 P-scratch with
// conflict-reduced slot = ((tt>>3)+qq+(qq>>3))&7; defer-max; setprio. 80KB.
// ---------------------------------------------------------------------------
__global__ __launch_bounds__(512, 4) void attn_kernel(
    const __hip_bfloat16* __restrict__ Qm, const __hip_bfloat16* __restrict__ Km,
    const __hip_bfloat16* __restrict__ Vt, __hip_bfloat16* __restrict__ Om) {
  __shared__ __align__(16) unsigned char Kl[2][16384];  // [64 t][128 d] swizzled
  __shared__ __align__(16) unsigned char Vl[2][16384];  // [128 d][64 t] swizzled
  __shared__ __align__(16) unsigned char Pl[16384];     // per-wave 2KB bf16 [16 q][64 t]
  const int tid = threadIdx.x;
  const int lane = tid & 63, w = tid >> 6;  // w in 0..7
  const int l15 = lane & 15, lg = lane >> 4;
  const int bh = blockIdx.y, b = bh >> 4, h = bh & 15;
  const int q0 = ((int)gridDim.x - 1 - (int)blockIdx.x) * 128;  // LPT order
  const int qw = q0 + w * 16;
  const int row8 = lane >> 3;
  const int nt = (q0 >> 6) + 2;  // K/V tiles 0 .. q0/64+1

  // Q fragments (A-operand): row = l15, k = ks*32 + lg*8 .. +8
  short8 qf[4];
  const __hip_bfloat16* qbase = Qm + (size_t)(b * SEQ + qw + l15) * D_MODEL + h * DK;
#pragma unroll
  for (int ks = 0; ks < 4; ++ks) qf[ks] = *(const short8*)(qbase + ks * 32 + lg * 8);

  float m_run[4], l_run[4];
  f32x4 acc_o[8];
#pragma unroll
  for (int r = 0; r < 4; ++r) { m_run[r] = -1e30f; l_run[r] = 0.0f; }
#pragma unroll
  for (int fd = 0; fd < 8; ++fd) acc_o[fd] = (f32x4){0.f, 0.f, 0.f, 0.f};

  auto STAGE = [&](int tt) {
    unsigned char* kb = Kl[tt & 1];
    unsigned char* vb = Vl[tt & 1];
    const int t0 = tt * 64;
#pragma unroll
    for (int i = 0; i < 2; ++i) {
      const int c = w * 2 + i;
      const int row = c * 4 + lg;
      const int gcb = l15 ^ (row & 7);
      GLOAD16(Km + (size_t)(b * SEQ + t0 + row) * D_MODEL + h * DK + gcb * 8,
              kb + c * 1024);
    }
#pragma unroll
    for (int i = 0; i < 2; ++i) {
      const int c = w * 2 + i;
      const int row = c * 8 + row8;
      const int gcb = (lane & 7) ^ (row & 7);
      GLOAD16(Vt + (size_t)(bh * DK + row) * SEQ + t0 + gcb * 8, vb + c * 1024);
    }
  };

  STAGE(0);
  for (int t = 0; t < nt; ++t) {
    const int t0 = t * 64;
    if (t + 1 < nt) {
      STAGE(t + 1);  // 4 loads -> in flight across this tile's compute
      asm volatile("s_waitcnt vmcnt(4)" ::: "memory");  // tile t complete
    } else {
      asm volatile("s_waitcnt vmcnt(0)" ::: "memory");
    }
    __builtin_amdgcn_s_barrier();  // all waves: tile t in LDS; t-1 reads done
    asm volatile("" ::: "memory");
    if (t0 <= qw + 15) {
      const unsigned char* kb = Kl[t & 1];
      const unsigned char* vb = Vl[t & 1];
      // S = Q K^T  (output: row q = lg*4+r, col key = l15 within frag fn)
      f32x4 sacc[4];
#pragma unroll
      for (int fn = 0; fn < 4; ++fn) sacc[fn] = (f32x4){0.f, 0.f, 0.f, 0.f};
      __builtin_amdgcn_s_setprio(1);
#pragma unroll
      for (int ks = 0; ks < 4; ++ks) {
        const int cb = ks * 4 + lg;
#pragma unroll
        for (int fn = 0; fn < 4; ++fn) {
          const int rn = fn * 16 + l15;
          short8 kf = *(const short8*)(kb + rn * 256 + ((cb ^ (rn & 7)) << 4));
          sacc[fn] = MFMA16(qf[ks], kf, sacc[fn]);
        }
      }
      __builtin_amdgcn_s_setprio(0);
      const float scale = 0.088388347648318447f;  // 1/sqrt(128)
      float mt[4] = {-1e30f, -1e30f, -1e30f, -1e30f};
#pragma unroll
      for (int fn = 0; fn < 4; ++fn) {
        const int key = t0 + fn * 16 + l15;
#pragma unroll
        for (int r = 0; r < 4; ++r) {
          const int qg = qw + lg * 4 + r;
          float sv = sacc[fn][r] * scale;
          sv = (key <= qg) ? sv : -1e30f;
          sacc[fn][r] = sv;
          mt[r] = fmaxf(mt[r], sv);
        }
      }
#pragma unroll
      for (int r = 0; r < 4; ++r)
#pragma unroll
        for (int off = 1; off < 16; off <<= 1) mt[r] = fmaxf(mt[r], __shfl_xor(mt[r], off));
      // defer-max (T13): skip rescale when tile max is within THR of running max
      int ok = 1;
#pragma unroll
      for (int r = 0; r < 4; ++r) ok = ok && (mt[r] <= m_run[r] + 8.0f);
      const bool defer = __all(ok);
      float alpha[4];
      if (!defer) {
#pragma unroll
        for (int r = 0; r < 4; ++r) {
          const float mnew = fmaxf(m_run[r], mt[r]);
          alpha[r] = __expf(m_run[r] - mnew);
          m_run[r] = mnew;
        }
      }
      float ls[4] = {0.f, 0.f, 0.f, 0.f};
#pragma unroll
      for (int fn = 0; fn < 4; ++fn)
#pragma unroll
        for (int r = 0; r < 4; ++r) {
          const float p = __expf(sacc[fn][r] - m_run[r]);
          sacc[fn][r] = p;
          ls[r] += p;
        }
#pragma unroll
      for (int r = 0; r < 4; ++r) {
#pragma unroll
        for (int off = 1; off < 16; off <<= 1) ls[r] += __shfl_xor(ls[r], off);
        l_run[r] = (defer ? l_run[r] : l_run[r] * alpha[r]) + ls[r];
      }
      if (!defer) {
#pragma unroll
        for (int fd = 0; fd < 8; ++fd)
#pragma unroll
          for (int r = 0; r < 4; ++r) acc_o[fd][r] *= alpha[r];
      }
      // write P (bf16): row q (128B), slot = ((tt>>3)+qq+(qq>>3))&7 (2-4 way)
      unsigned char* pw = Pl + w * 2048;
#pragma unroll
      for (int fn = 0; fn < 4; ++fn) {
        const int tt = fn * 16 + l15;
#pragma unroll
        for (int r = 0; r < 4; ++r) {
          const int qq = lg * 4 + r;
          *(unsigned short*)(pw + qq * 128 +
                             ((((tt >> 3) + qq + (qq >> 3)) & 7) << 4) +
                             (tt & 7) * 2) = f2bf(sacc[fn][r]);
        }
      }
      // O += P V  (A-operand P: row q = l15, k-slot tb = ks*4+lg)
#pragma unroll
      for (int ks = 0; ks < 2; ++ks) {
        const int tb = ks * 4 + lg;
        short8 pf = *(const short8*)(Pl + w * 2048 + l15 * 128 +
                                     (((tb + l15 + (l15 >> 3)) & 7) << 4));
        const int cb = ks * 4 + lg;
        __builtin_amdgcn_s_setprio(1);
#pragma unroll
        for (int fd = 0; fd < 8; ++fd) {
          const int rv = fd * 16 + l15;
          short8 vf = *(const short8*)(vb + rv * 128 + ((cb ^ (rv & 7)) << 4));
          acc_o[fd] = MFMA16(pf, vf, acc_o[fd]);
        }
        __builtin_amdgcn_s_setprio(0);
      }
    }
    asm volatile("" ::: "memory");
    __builtin_amdgcn_s_barrier();  // all reads of buf[t&1] done before t+2 stages it
    asm volatile("" ::: "memory");
  }
#pragma unroll
  for (int r = 0; r < 4; ++r) {
    const float inv = 1.0f / l_run[r];
    const int qg = qw + lg * 4 + r;
    __hip_bfloat16* ob = Om + (size_t)(b * SEQ + qg) * D_MODEL + h * DK + l15;
#pragma unroll
    for (int fd = 0; fd < 8; ++fd)
      ob[fd * 16] = __float2bfloat16(acc_o[fd][r] * inv);
  }
}

// ---------------------------------------------------------------------------
// Workspace layout (192 MiB peak, time-shared):
//   @0   Hb (32M)  LN1 out -> later LN2 out
//   @32  Qb (32M) -\
//   @64  Kb (32M)  |-> after O-proj: FF1 full tensor (128M, 8192x8192 bf16)
//   @96  Vt (32M)  |
//   @128 AO (32M) -/
//   @160 WqT/WkT/WvT/WoT (4x8M) -> after O-proj: W1T (32M) -> after FF1: W2T (32M)
// X2 (f32 residual stream) lives in d_out itself.
// ---------------------------------------------------------------------------
extern "C" void kernel_launch(void* const* d_in, const int* in_sizes, int n_in,
                              void* d_out, int out_size, void* d_ws, size_t ws_size,
                              hipStream_t stream) {
  (void)in_sizes; (void)n_in; (void)out_size;
  const size_t MB = 1024 * 1024;
  if (ws_size < 192 * MB) return;  // diagnostic guard

  const float* x  = (const float*)d_in[0];
  const float* Wq = (const float*)d_in[1];
  const float* bq = (const float*)d_in[2];
  const float* Wk = (const float*)d_in[3];
  const float* bk = (const float*)d_in[4];
  const float* Wv = (const float*)d_in[5];
  const float* bv = (const float*)d_in[6];
  const float* Wo = (const float*)d_in[7];
  const float* bo = (const float*)d_in[8];
  const float* W1 = (const float*)d_in[9];
  const float* b1 = (const float*)d_in[10];
  const float* W2 = (const float*)d_in[11];
  const float* b2 = (const float*)d_in[12];
  const float* g1 = (const float*)d_in[13];
  const float* be1 = (const float*)d_in[14];
  const float* g2 = (const float*)d_in[15];
  const float* be2 = (const float*)d_in[16];

  char* ws = (char*)d_ws;
  __hip_bfloat16* Hb  = (__hip_bfloat16*)(ws + 0 * MB);
  __hip_bfloat16* Qb  = (__hip_bfloat16*)(ws + 32 * MB);
  __hip_bfloat16* Kb  = (__hip_bfloat16*)(ws + 64 * MB);
  __hip_bfloat16* Vtb = (__hip_bfloat16*)(ws + 96 * MB);
  __hip_bfloat16* AOb = (__hip_bfloat16*)(ws + 128 * MB);
  __hip_bfloat16* FF1 = (__hip_bfloat16*)(ws + 32 * MB);   // after O-proj, 128M
  __hip_bfloat16* WqT = (__hip_bfloat16*)(ws + 160 * MB);
  __hip_bfloat16* WkT = (__hip_bfloat16*)(ws + 168 * MB);
  __hip_bfloat16* WvT = (__hip_bfloat16*)(ws + 176 * MB);
  __hip_bfloat16* WoT = (__hip_bfloat16*)(ws + 184 * MB);
  __hip_bfloat16* W1T = (__hip_bfloat16*)(ws + 160 * MB);  // after O-proj
  __hip_bfloat16* W2T = (__hip_bfloat16*)(ws + 160 * MB);  // after FF1
  float* X2 = (float*)d_out;  // residual stream lives in d_out

  const dim3 tb(256);
  transpose_cvt_kernel<<<dim3(64, 64), tb, 0, stream>>>(Wq, WqT, 2048, 2048);
  transpose_cvt_kernel<<<dim3(64, 64), tb, 0, stream>>>(Wk, WkT, 2048, 2048);
  transpose_cvt_kernel<<<dim3(64, 64), tb, 0, stream>>>(Wv, WvT, 2048, 2048);
  transpose_cvt_kernel<<<dim3(64, 64), tb, 0, stream>>>(Wo, WoT, 2048, 2048);

  layernorm_kernel<<<MTOT, tb, 0, stream>>>(x, g1, be1, Hb);

  // QKV/O-proj: M=8192, N=2048 -> 256 blocks (XCD window 4r x 8c)
  gemm_kernel<EPI_BF16><<<256, 512, 0, stream>>>(Hb, WqT, bq, nullptr, Qb, MTOT, 2048, 2048);
  gemm_kernel<EPI_BF16><<<256, 512, 0, stream>>>(Hb, WkT, bk, nullptr, Kb, MTOT, 2048, 2048);
  gemm_kernel<EPI_VT><<<256, 512, 0, stream>>>(Hb, WvT, bv, nullptr, Vtb, MTOT, 2048, 2048);

  attn_kernel<<<dim3(SEQ / 128, BATCH * NUM_HEADS), dim3(512), 0, stream>>>(Qb, Kb, Vtb, AOb);

  gemm_kernel<EPI_RESID><<<256, 512, 0, stream>>>(AOb, WoT, bo, x, X2, MTOT, 2048, 2048);

  layernorm_kernel<<<MTOT, tb, 0, stream>>>(X2, g2, be2, Hb);

  // FFN full-M: W1T into dead small-weight region, FF1 into dead Q/K/Vt/AO
  transpose_cvt_kernel<<<dim3(256, 64), tb, 0, stream>>>(W1, W1T, 2048, 8192);
  // FF1: M=8192, N=8192 -> 1024 blocks
  gemm_kernel<EPI_GELU><<<1024, 512, 0, stream>>>(Hb, W1T, b1, nullptr, FF1, MTOT, 8192, 2048);
  // W2T overwrites W1T (dead after FF1)
  transpose_cvt_kernel<<<dim3(64, 256), tb, 0, stream>>>(W2, W2T, 8192, 2048);
  // FF2: M=8192, N=2048, K=8192 -> 256 blocks
  gemm_kernel<EPI_RESID><<<256, 512, 0, stream>>>(FF1, W2T, b2, X2, X2, MTOT, 2048, 8192);
}